// Round 13
// baseline (425.351 us; speedup 1.0000x reference)
//
#include <hip/hip_runtime.h>
#include <hip/hip_bf16.h>
#include <stdint.h>

// Problem dims (fixed by the reference)
#define DM 768
#define DI 1536
#define DSTATE 16
#define RNK 48
#define BB 2
#define LL 1024
#define ML (BB * LL)  // 2048 rows (b*l flattened)

// segmented scan config
#define NSEG 32
#define SEGL (LL / NSEG)   // 32

typedef unsigned short u16;
typedef __bf16 bf16x8 __attribute__((ext_vector_type(8)));
typedef float f32x4 __attribute__((ext_vector_type(4)));

struct __align__(8) u16x4_t { u16 x, y, z, w; };

__device__ __forceinline__ float b2f(u16 u) {
  union { uint32_t i; float f; } v; v.i = ((uint32_t)u) << 16; return v.f;
}
__device__ __forceinline__ u16 f2b(float f) {
  union { float f; uint32_t i; } v; v.f = f;
  uint32_t r = v.i + 0x7FFFu + ((v.i >> 16) & 1u);  // RNE
  return (u16)(r >> 16);
}
__device__ __forceinline__ float silu_f(float x) { return x / (1.f + __expf(-x)); }
__device__ __forceinline__ float softplus_f(float s) {
  return fmaxf(s, 0.f) + __logf(1.f + __expf(-fabsf(s)));
}
__device__ __forceinline__ u16x4_t cvt4(float4 v) {
  u16x4_t o; o.x = f2b(v.x); o.y = f2b(v.y); o.z = f2b(v.z); o.w = f2b(v.w); return o;
}

// ---------------------------------------------------------------------------
// Fused fp32->bf16 conversion of GEMM operands + small-weight packing.
// wcat (128x1536): rows 0..15=W_B, 16..31=W_C, 32..79=W_dt, 80..127=0
// dtWb (1536x64):  cols 0..47=dtW row, 48..63=0
// ---------------------------------------------------------------------------
#define SEG_X    (ML * DM / 4)
#define SEG_W    (DI * DM / 4)
#define SEG_CAT  (128 * DI / 4)
#define SEG_DTW  (DI * 64 / 4)
__global__ __launch_bounds__(256) void convert_kernel(
    const float4* __restrict__ x, const float4* __restrict__ wis,
    const float4* __restrict__ wig, const float4* __restrict__ wout,
    const float* __restrict__ W_B, const float* __restrict__ W_C,
    const float* __restrict__ W_dt,
    const float* __restrict__ W_B_b, const float* __restrict__ W_C_b,
    const float* __restrict__ W_dt_b,
    const float* __restrict__ dtW, const float* __restrict__ dtW_b,
    u16x4_t* __restrict__ xb, u16x4_t* __restrict__ wisb,
    u16x4_t* __restrict__ wigb, u16x4_t* __restrict__ woutb,
    u16x4_t* __restrict__ wcf, u16x4_t* __restrict__ wcb,
    u16x4_t* __restrict__ dtwf, u16x4_t* __restrict__ dtwb)
{
  int idx = blockIdx.x * 256 + threadIdx.x;
  if (idx < SEG_X) { xb[idx] = cvt4(x[idx]); return; }
  idx -= SEG_X;
  if (idx < SEG_W) { wisb[idx] = cvt4(wis[idx]); return; }
  idx -= SEG_W;
  if (idx < SEG_W) { wigb[idx] = cvt4(wig[idx]); return; }
  idx -= SEG_W;
  if (idx < SEG_W) { woutb[idx] = cvt4(wout[idx]); return; }
  idx -= SEG_W;
  if (idx < 2 * SEG_CAT) {
    int dir = idx / SEG_CAT;
    int rem = idx % SEG_CAT;
    int row = rem / (DI / 4), k4 = rem % (DI / 4);
    const float* src = nullptr;
    if (row < 16)      src = (dir ? W_B_b  : W_B)  + (size_t)row * DI + k4 * 4;
    else if (row < 32) src = (dir ? W_C_b  : W_C)  + (size_t)(row - 16) * DI + k4 * 4;
    else if (row < 80) src = (dir ? W_dt_b : W_dt) + (size_t)(row - 32) * DI + k4 * 4;
    u16x4_t o;
    if (src) o = cvt4(*(const float4*)src);
    else { o.x = 0; o.y = 0; o.z = 0; o.w = 0; }
    (dir ? wcb : wcf)[rem] = o;
    return;
  }
  idx -= 2 * SEG_CAT;
  int dir = idx / SEG_DTW;
  int rem = idx % SEG_DTW;
  int d = rem / 16, r4 = rem % 16;
  const float* Dw = dir ? dtW_b : dtW;
  u16x4_t o;
  if (r4 < 12) o = cvt4(*(const float4*)(Dw + (size_t)d * RNK + r4 * 4));
  else { o.x = 0; o.y = 0; o.z = 0; o.w = 0; }
  (dir ? dtwb : dtwf)[rem] = o;
}

// ---------------------------------------------------------------------------
// Generic bf16 GEMM: C = A (MxK) @ B^T (NxK). 128x128 tile, 4 waves,
// 16x16x32 MFMA, reg double-buffer pipeline.
// epi: 0 bf16 (dual-B silu via B1/Nsplit) | 2 fp32 | 6 fp32 softplus(acc+ebias[col])
// blockIdx.z==1 switches to (A2,B2,C2,ebias2).
// ---------------------------------------------------------------------------
__global__ __launch_bounds__(256) void gemm_bt(
    const u16* __restrict__ A, const u16* __restrict__ B0,
    const u16* __restrict__ B1, int Nsplit,
    void* __restrict__ Cout, int M, int N, int K, int ldc, int epi,
    const u16* __restrict__ A2, const u16* __restrict__ B2,
    void* __restrict__ C2,
    const float* __restrict__ ebias, const float* __restrict__ ebias2)
{
  if (blockIdx.z) { A = A2; B0 = B2; Cout = C2; ebias = ebias2; }
  __shared__ alignas(16) u16 As[128 * 32];
  __shared__ alignas(16) u16 Bs[128 * 32];
  const int tid = threadIdx.x;
  const int wave = tid >> 6, lane = tid & 63;
  const int bm = blockIdx.y * 128;
  const int bn = blockIdx.x * 128;

  const u16* Bmat = B0;
  int ncol0 = bn;
  int epi_l = epi;
  if (B1 != nullptr && bn >= Nsplit) { Bmat = B1; ncol0 = bn - Nsplit; epi_l = 1; }

  const int c0 = tid, c1 = tid + 256;
  const u16* gA0 = A + (size_t)(bm + (c0 >> 2)) * K + (c0 & 3) * 8;
  const u16* gA1 = A + (size_t)(bm + (c1 >> 2)) * K + (c1 & 3) * 8;
  const u16* gB0 = Bmat + (size_t)(ncol0 + (c0 >> 2)) * K + (c0 & 3) * 8;
  const u16* gB1 = Bmat + (size_t)(ncol0 + (c1 >> 2)) * K + (c1 & 3) * 8;
  uint4* lA0 = (uint4*)&As[c0 * 8]; uint4* lA1 = (uint4*)&As[c1 * 8];
  uint4* lB0 = (uint4*)&Bs[c0 * 8]; uint4* lB1 = (uint4*)&Bs[c1 * 8];

  const int wm = (wave & 1) * 64, wn = (wave >> 1) * 64;
  const int rl = lane & 15, q = lane >> 4;

  f32x4 acc[4][4];
#pragma unroll
  for (int i = 0; i < 4; ++i)
#pragma unroll
    for (int j = 0; j < 4; ++j) acc[i][j] = (f32x4){0.f, 0.f, 0.f, 0.f};

  const bf16x8* AsV = (const bf16x8*)As;
  const bf16x8* BsV = (const bf16x8*)Bs;

  uint4 ra0 = *(const uint4*)(gA0);
  uint4 ra1 = *(const uint4*)(gA1);
  uint4 rb0 = *(const uint4*)(gB0);
  uint4 rb1 = *(const uint4*)(gB1);

  for (int k0 = 0; k0 < K; k0 += 32) {
    *lA0 = ra0; *lA1 = ra1; *lB0 = rb0; *lB1 = rb1;
    __syncthreads();
    if (k0 + 32 < K) {
      ra0 = *(const uint4*)(gA0 + k0 + 32);
      ra1 = *(const uint4*)(gA1 + k0 + 32);
      rb0 = *(const uint4*)(gB0 + k0 + 32);
      rb1 = *(const uint4*)(gB1 + k0 + 32);
    }
    bf16x8 af[4], bfv[4];
#pragma unroll
    for (int s = 0; s < 4; ++s) {
      af[s]  = AsV[(wm + s * 16 + rl) * 4 + q];
      bfv[s] = BsV[(wn + s * 16 + rl) * 4 + q];
    }
#pragma unroll
    for (int i = 0; i < 4; ++i)
#pragma unroll
      for (int j = 0; j < 4; ++j)
        acc[i][j] = __builtin_amdgcn_mfma_f32_16x16x32_bf16(af[i], bfv[j], acc[i][j], 0, 0, 0);
    __syncthreads();
  }

#pragma unroll
  for (int i = 0; i < 4; ++i) {
#pragma unroll
    for (int j = 0; j < 4; ++j) {
#pragma unroll
      for (int r = 0; r < 4; ++r) {
        int row = bm + wm + i * 16 + q * 4 + r;
        int col = bn + wn + j * 16 + rl;
        float v = acc[i][j][r];
        if (epi_l == 1) v = silu_f(v);
        if (epi == 6)      ((float*)Cout)[(size_t)row * ldc + col] = softplus_f(v + ebias[col]);
        else if (epi == 2) ((float*)Cout)[(size_t)row * ldc + col] = v;
        else               ((u16*)Cout)[(size_t)row * ldc + col] = f2b(v);
      }
    }
  }
}

// ---------------------------------------------------------------------------
// Proj GEMM with FUSED causal conv+SiLU in the A-staging (N-grid must be 1 so
// each A element is computed once). A[row, k] = silu(conv(xs)[row, k]).
// dir=0: fwd conv; dir=1: conv on reversed sequence via
//   xcb[j,d] = silu(cbb[d] + sum_k wbk[k] * xs[L+2-j-k, d])  (taps j-3+k>=0)
// Output epi: col<32 fp32->[B|C] (ld 32); 32<=col<96 bf16 dt_low (ld 64).
// ---------------------------------------------------------------------------
__global__ __launch_bounds__(256) void gemm_projconv(
    const u16* __restrict__ xsg,
    const u16* __restrict__ wcf, const u16* __restrict__ wcb,
    const float* __restrict__ cw, const float* __restrict__ cb,
    const float* __restrict__ cwb, const float* __restrict__ cbb,
    float* __restrict__ pf, float* __restrict__ pb,
    u16* __restrict__ dtlf, u16* __restrict__ dtlb)
{
  const int dir = blockIdx.z;
  const u16* Bmat = dir ? wcb : wcf;
  const float* cwp = dir ? cwb : cw;
  const float* cbp = dir ? cbb : cb;
  float* Cout = dir ? pb : pf;
  u16* Caux = dir ? dtlb : dtlf;

  __shared__ alignas(16) u16 As[128 * 32];
  __shared__ alignas(16) u16 Bs[128 * 32];
  __shared__ alignas(16) u16 Xs[131 * 32];
  __shared__ float Wsh[32][4];
  __shared__ float Bish[32];

  const int tid = threadIdx.x;
  const int wave = tid >> 6, lane = tid & 63;
  const int bm = blockIdx.y * 128;
  const int bb = bm / LL, l0 = bm % LL;

  const int c0 = tid, c1 = tid + 256;
  const u16* gB0 = Bmat + (size_t)(c0 >> 2) * DI + (c0 & 3) * 8;
  const u16* gB1 = Bmat + (size_t)(c1 >> 2) * DI + (c1 & 3) * 8;
  uint4* lB0 = (uint4*)&Bs[c0 * 8]; uint4* lB1 = (uint4*)&Bs[c1 * 8];

  // xs tile: 524 chunks of 16B; this thread's chunks (up to 3)
  const u16* gX[3]; uint4* lX[3]; int nxc = 0;
  for (int c = tid; c < 524; c += 256) {
    int trow = c >> 2, dc = (c & 3) * 8;
    int ls = dir ? (LL - 128 - l0 + trow) : (l0 - 3 + trow);
    gX[nxc] = (ls >= 0 && ls < LL)
        ? xsg + (size_t)(bb * LL + ls) * 3072 + dc : nullptr;
    lX[nxc] = (uint4*)&Xs[(size_t)c * 8];
    nxc++;
  }

  const int wm = (wave & 1) * 64, wn = (wave >> 1) * 64;
  const int rl = lane & 15, q = lane >> 4;

  f32x4 acc[4][4];
#pragma unroll
  for (int i = 0; i < 4; ++i)
#pragma unroll
    for (int j = 0; j < 4; ++j) acc[i][j] = (f32x4){0.f, 0.f, 0.f, 0.f};

  const bf16x8* AsV = (const bf16x8*)As;
  const bf16x8* BsV = (const bf16x8*)Bs;
  const uint4 zz = {0u, 0u, 0u, 0u};

  // prologue (k0 = 0)
  uint4 rb0 = *(const uint4*)gB0;
  uint4 rb1 = *(const uint4*)gB1;
  uint4 rx[3];
  for (int i = 0; i < nxc; ++i) rx[i] = gX[i] ? *(const uint4*)(gX[i]) : zz;
  float wreg = 0.f, breg = 0.f;
  if (tid < 128)       wreg = cwp[(size_t)(tid >> 2) * 4 + (tid & 3)];
  else if (tid < 160)  breg = cbp[tid - 128];

  for (int k0 = 0; k0 < DI; k0 += 32) {
    *lB0 = rb0; *lB1 = rb1;
    for (int i = 0; i < nxc; ++i) *lX[i] = rx[i];
    if (tid < 128)      Wsh[tid >> 2][tid & 3] = wreg;
    else if (tid < 160) Bish[tid - 128] = breg;
    __syncthreads();

    if (k0 + 32 < DI) {
      rb0 = *(const uint4*)(gB0 + k0 + 32);
      rb1 = *(const uint4*)(gB1 + k0 + 32);
      for (int i = 0; i < nxc; ++i)
        rx[i] = gX[i] ? *(const uint4*)(gX[i] + k0 + 32) : zz;
      if (tid < 128)      wreg = cwp[(size_t)(k0 + 32 + (tid >> 2)) * 4 + (tid & 3)];
      else if (tid < 160) breg = cbp[k0 + 32 + tid - 128];
    }

    // conv -> As (chunks c0, c1)
#pragma unroll
    for (int cc = 0; cc < 2; ++cc) {
      int c = cc ? c1 : c0;
      int i = c >> 2, dl = (c & 3) * 8;
      int outl = l0 + i;                   // output seq index (both dirs)
      uint4 x4[4];
#pragma unroll
      for (int k = 0; k < 4; ++k) {
        int t = dir ? (130 - i - k) : (i + k);
        x4[k] = *(const uint4*)&Xs[(size_t)t * 32 + dl];
      }
      u16 ov[8];
#pragma unroll
      for (int e = 0; e < 8; ++e) {
        float a = Bish[dl + e];
#pragma unroll
        for (int k = 0; k < 4; ++k) {
          const u16* xp = (const u16*)&x4[k];
          float tap = (outl + k >= 3) ? b2f(xp[e]) : 0.f;
          a += Wsh[dl + e][k] * tap;
        }
        ov[e] = f2b(silu_f(a));
      }
      *(uint4*)&As[(size_t)c * 8] = *(const uint4*)ov;
    }
    __syncthreads();

    bf16x8 af[4], bfv[4];
#pragma unroll
    for (int s = 0; s < 4; ++s) {
      af[s]  = AsV[(wm + s * 16 + rl) * 4 + q];
      bfv[s] = BsV[(wn + s * 16 + rl) * 4 + q];
    }
#pragma unroll
    for (int i = 0; i < 4; ++i)
#pragma unroll
      for (int j = 0; j < 4; ++j)
        acc[i][j] = __builtin_amdgcn_mfma_f32_16x16x32_bf16(af[i], bfv[j], acc[i][j], 0, 0, 0);
    __syncthreads();
  }

#pragma unroll
  for (int i = 0; i < 4; ++i) {
#pragma unroll
    for (int j = 0; j < 4; ++j) {
#pragma unroll
      for (int r = 0; r < 4; ++r) {
        int row = bm + wm + i * 16 + q * 4 + r;
        int col = wn + j * 16 + rl;
        float v = acc[i][j][r];
        if (col < 32)      Cout[(size_t)row * 32 + col] = v;
        else if (col < 96) Caux[(size_t)row * 64 + (col - 32)] = f2b(v);
      }
    }
  }
}

// ---------------------------------------------------------------------------
// Out-proj GEMM with FUSED gated combine in A-staging:
// A[row,k] = 0.5*(yf[row,k] + ybr[rev(row),k]) * gate[row,k]; fp32 out.
// ---------------------------------------------------------------------------
__global__ __launch_bounds__(256) void gemm_out(
    const u16* __restrict__ yf, const u16* __restrict__ ybr,
    const u16* __restrict__ xsg, const u16* __restrict__ Bw,
    float* __restrict__ out)
{
  __shared__ alignas(16) u16 As[128 * 32];
  __shared__ alignas(16) u16 Bs[128 * 32];
  const int tid = threadIdx.x;
  const int wave = tid >> 6, lane = tid & 63;
  const int bm = blockIdx.y * 128;
  const int bn = blockIdx.x * 128;

  const int c0 = tid, c1 = tid + 256;
  int r0 = bm + (c0 >> 2), r1 = bm + (c1 >> 2);
  int dc0 = (c0 & 3) * 8, dc1 = (c1 & 3) * 8;
  int rr0 = (r0 / LL) * LL + (LL - 1 - (r0 % LL));
  int rr1 = (r1 / LL) * LL + (LL - 1 - (r1 % LL));
  const u16* gy0 = yf + (size_t)r0 * DI + dc0;
  const u16* gy1 = yf + (size_t)r1 * DI + dc1;
  const u16* gr0 = ybr + (size_t)rr0 * DI + dc0;
  const u16* gr1 = ybr + (size_t)rr1 * DI + dc1;
  const u16* gg0 = xsg + (size_t)r0 * 3072 + DI + dc0;
  const u16* gg1 = xsg + (size_t)r1 * 3072 + DI + dc1;
  const u16* gB0 = Bw + (size_t)(bn + (c0 >> 2)) * DI + dc0;
  const u16* gB1 = Bw + (size_t)(bn + (c1 >> 2)) * DI + dc1;
  uint4* lA0 = (uint4*)&As[c0 * 8]; uint4* lA1 = (uint4*)&As[c1 * 8];
  uint4* lB0 = (uint4*)&Bs[c0 * 8]; uint4* lB1 = (uint4*)&Bs[c1 * 8];

  const int wm = (wave & 1) * 64, wn = (wave >> 1) * 64;
  const int rl = lane & 15, q = lane >> 4;

  f32x4 acc[4][4];
#pragma unroll
  for (int i = 0; i < 4; ++i)
#pragma unroll
    for (int j = 0; j < 4; ++j) acc[i][j] = (f32x4){0.f, 0.f, 0.f, 0.f};

  const bf16x8* AsV = (const bf16x8*)As;
  const bf16x8* BsV = (const bf16x8*)Bs;

  uint4 ry0 = *(const uint4*)gy0, ry1 = *(const uint4*)gy1;
  uint4 rr0v = *(const uint4*)gr0, rr1v = *(const uint4*)gr1;
  uint4 rg0 = *(const uint4*)gg0, rg1 = *(const uint4*)gg1;
  uint4 rb0 = *(const uint4*)gB0, rb1 = *(const uint4*)gB1;

  for (int k0 = 0; k0 < DI; k0 += 32) {
    // combine -> As
    {
      const u16* yp0 = (const u16*)&ry0; const u16* bp0 = (const u16*)&rr0v;
      const u16* gp0 = (const u16*)&rg0;
      const u16* yp1 = (const u16*)&ry1; const u16* bp1 = (const u16*)&rr1v;
      const u16* gp1 = (const u16*)&rg1;
      u16 o0[8], o1[8];
#pragma unroll
      for (int e = 0; e < 8; ++e) {
        o0[e] = f2b(0.5f * (b2f(yp0[e]) + b2f(bp0[e])) * b2f(gp0[e]));
        o1[e] = f2b(0.5f * (b2f(yp1[e]) + b2f(bp1[e])) * b2f(gp1[e]));
      }
      *lA0 = *(const uint4*)o0;
      *lA1 = *(const uint4*)o1;
    }
    *lB0 = rb0; *lB1 = rb1;
    __syncthreads();
    if (k0 + 32 < DI) {
      ry0 = *(const uint4*)(gy0 + k0 + 32); ry1 = *(const uint4*)(gy1 + k0 + 32);
      rr0v = *(const uint4*)(gr0 + k0 + 32); rr1v = *(const uint4*)(gr1 + k0 + 32);
      rg0 = *(const uint4*)(gg0 + k0 + 32); rg1 = *(const uint4*)(gg1 + k0 + 32);
      rb0 = *(const uint4*)(gB0 + k0 + 32); rb1 = *(const uint4*)(gB1 + k0 + 32);
    }
    bf16x8 af[4], bfv[4];
#pragma unroll
    for (int s = 0; s < 4; ++s) {
      af[s]  = AsV[(wm + s * 16 + rl) * 4 + q];
      bfv[s] = BsV[(wn + s * 16 + rl) * 4 + q];
    }
#pragma unroll
    for (int i = 0; i < 4; ++i)
#pragma unroll
      for (int j = 0; j < 4; ++j)
        acc[i][j] = __builtin_amdgcn_mfma_f32_16x16x32_bf16(af[i], bfv[j], acc[i][j], 0, 0, 0);
    __syncthreads();
  }

#pragma unroll
  for (int i = 0; i < 4; ++i) {
#pragma unroll
    for (int j = 0; j < 4; ++j) {
#pragma unroll
      for (int r = 0; r < 4; ++r) {
        int row = bm + wm + i * 16 + q * 4 + r;
        int col = bn + wn + j * 16 + rl;
        out[(size_t)row * DM + col] = acc[i][j][r];
      }
    }
  }
}

// ---------------------------------------------------------------------------
// Segmented scan, phase A, with INLINE conv (sliding 4-reg window over xsg).
// delta precomputed fp32 (softplus in delta-GEMM epilogue).
// ---------------------------------------------------------------------------
__global__ __launch_bounds__(256) void scan_sum(
    const u16* __restrict__ xsg,
    const float* __restrict__ cw, const float* __restrict__ cb,
    const float* __restrict__ cwb, const float* __restrict__ cbb,
    const float* __restrict__ df, const float* __restrict__ db,
    const float* __restrict__ pf, const float* __restrict__ pb,
    const float* __restrict__ A_log, const float* __restrict__ A_log_b,
    float* __restrict__ sdl, float* __restrict__ bs)
{
  const int dir = blockIdx.z / NSEG, seg = blockIdx.z % NSEG;
  const float* delta = dir ? db : df;
  const float* proj = dir ? pb : pf;
  const float* Al = dir ? A_log_b : A_log;
  const int b = blockIdx.y;
  const int d = blockIdx.x * 256 + threadIdx.x;
  const int l0 = seg * SEGL;

  __shared__ float Bsh[SEGL][16];
  for (int i = threadIdx.x; i < SEGL * 16; i += 256) {
    int l = i >> 4, n = i & 15;
    Bsh[l][n] = proj[((size_t)b * LL + l0 + l) * 32 + n];
  }
  __syncthreads();

  float An[16];
#pragma unroll
  for (int n = 0; n < 16; ++n) An[n] = -__expf(Al[d * 16 + n]);

  float4 wv = dir ? *(const float4*)(cwb + d * 4) : *(const float4*)(cw + d * 4);
  const float cbv = dir ? cbb[d] : cb[d];
  const u16* xcol = xsg + (size_t)b * LL * 3072 + d;

  // window init: w[k] = xs at the k-th conv tap of the first step
  float w[4];
#pragma unroll
  for (int k = 0; k < 4; ++k) {
    if (!dir) { int ls = l0 - 3 + k; w[k] = (ls >= 0) ? b2f(xcol[(size_t)ls * 3072]) : 0.f; }
    else      { int ls = LL + 2 - l0 - k; w[k] = (ls <= LL - 1) ? b2f(xcol[(size_t)ls * 3072]) : 0.f; }
  }

  float h[16];
#pragma unroll
  for (int n = 0; n < 16; ++n) h[n] = 0.f;
  float S = 0.f;

  const float* dbase = delta + ((size_t)b * LL + l0) * DI + d;

  for (int g = 0; g < SEGL; g += 4) {
    float dl4[4], nx[4];
#pragma unroll
    for (int j = 0; j < 4; ++j) {
      dl4[j] = dbase[(size_t)(g + j) * DI];
      int lnew = dir ? (LL - 2 - (l0 + g + j)) : (l0 + g + j + 1);
      bool ok = dir ? (lnew >= 0) : (lnew < LL);
      nx[j] = ok ? b2f(xcol[(size_t)lnew * 3072]) : 0.f;
    }
#pragma unroll
    for (int j = 0; j < 4; ++j) {
      float xv = silu_f(cbv + w[0] * wv.x + w[1] * wv.y + w[2] * wv.z + w[3] * wv.w);
      float dv = dl4[j];
      float dx = dv * xv;
      S += dv;
#pragma unroll
      for (int n = 0; n < 16; ++n)
        h[n] = __expf(dv * An[n]) * h[n] + dx * Bsh[g + j][n];
      w[0] = w[1]; w[1] = w[2]; w[2] = w[3]; w[3] = nx[j];
    }
  }

  size_t base = (((size_t)dir * BB + b) * NSEG + seg) * DI + d;
  sdl[base] = S;
#pragma unroll
  for (int n = 0; n < 16; ++n) bs[base * 16 + n] = h[n];
}

// ---------------------------------------------------------------------------
// Phase B: compose segment summaries into carry-ins (bs overwritten in place).
// ---------------------------------------------------------------------------
__global__ __launch_bounds__(256) void scan_carry(
    const float* __restrict__ A_log, const float* __restrict__ A_log_b,
    const float* __restrict__ sdl, float* __restrict__ bs)
{
  int idx = blockIdx.x * 256 + threadIdx.x;   // over 2*BB*DI*16
  int n = idx & 15;
  int t = idx >> 4;
  int d = t % DI;
  int b = (t / DI) % BB;
  int dir = t / (DI * BB);
  const float* Al = dir ? A_log_b : A_log;
  float An = -__expf(Al[d * 16 + n]);
  float h = 0.f;
  for (int s = 0; s < NSEG; ++s) {
    size_t base = (((size_t)dir * BB + b) * NSEG + s) * DI + d;
    float S = sdl[base];
    float bv = bs[base * 16 + n];
    bs[base * 16 + n] = h;
    h = __expf(S * An) * h + bv;
  }
}

// ---------------------------------------------------------------------------
// Phase C: recurrence from carry-in, compute y, with INLINE conv.
// ---------------------------------------------------------------------------
__global__ __launch_bounds__(256) void scan_apply(
    const u16* __restrict__ xsg,
    const float* __restrict__ cw, const float* __restrict__ cb,
    const float* __restrict__ cwb, const float* __restrict__ cbb,
    const float* __restrict__ df, const float* __restrict__ db,
    const float* __restrict__ pf, const float* __restrict__ pb,
    const float* __restrict__ A_log, const float* __restrict__ A_log_b,
    const float* __restrict__ Dp, const float* __restrict__ Dp_b,
    const float* __restrict__ bs,
    u16* __restrict__ y_f, u16* __restrict__ y_b)
{
  const int dir = blockIdx.z / NSEG, seg = blockIdx.z % NSEG;
  const float* delta = dir ? db : df;
  const float* proj = dir ? pb : pf;
  const float* Al = dir ? A_log_b : A_log;
  const float* Dpp = dir ? Dp_b : Dp;
  u16* y = dir ? y_b : y_f;
  const int b = blockIdx.y;
  const int d = blockIdx.x * 256 + threadIdx.x;
  const int l0 = seg * SEGL;

  __shared__ float BCsh[SEGL][32];
  for (int i = threadIdx.x; i < SEGL * 32; i += 256) {
    int l = i >> 5, j = i & 31;
    BCsh[l][j] = proj[((size_t)b * LL + l0 + l) * 32 + j];
  }
  __syncthreads();

  float An[16];
#pragma unroll
  for (int n = 0; n < 16; ++n) An[n] = -__expf(Al[d * 16 + n]);
  const float Dv = Dpp[d];

  float4 wv = dir ? *(const float4*)(cwb + d * 4) : *(const float4*)(cw + d * 4);
  const float cbv = dir ? cbb[d] : cb[d];
  const u16* xcol = xsg + (size_t)b * LL * 3072 + d;

  float w[4];
#pragma unroll
  for (int k = 0; k < 4; ++k) {
    if (!dir) { int ls = l0 - 3 + k; w[k] = (ls >= 0) ? b2f(xcol[(size_t)ls * 3072]) : 0.f; }
    else      { int ls = LL + 2 - l0 - k; w[k] = (ls <= LL - 1) ? b2f(xcol[(size_t)ls * 3072]) : 0.f; }
  }

  float h[16];
  size_t cbase = (((size_t)dir * BB + b) * NSEG + seg) * DI + d;
#pragma unroll
  for (int n = 0; n < 16; ++n) h[n] = bs[cbase * 16 + n];

  const float* dbase = delta + ((size_t)b * LL + l0) * DI + d;
  u16* ybase = y + ((size_t)b * LL + l0) * DI + d;

  for (int g = 0; g < SEGL; g += 4) {
    float dl4[4], nx[4];
#pragma unroll
    for (int j = 0; j < 4; ++j) {
      dl4[j] = dbase[(size_t)(g + j) * DI];
      int lnew = dir ? (LL - 2 - (l0 + g + j)) : (l0 + g + j + 1);
      bool ok = dir ? (lnew >= 0) : (lnew < LL);
      nx[j] = ok ? b2f(xcol[(size_t)lnew * 3072]) : 0.f;
    }
#pragma unroll
    for (int j = 0; j < 4; ++j) {
      float xv = silu_f(cbv + w[0] * wv.x + w[1] * wv.y + w[2] * wv.z + w[3] * wv.w);
      float dv = dl4[j];
      float dx = dv * xv;
      float yv = 0.f;
#pragma unroll
      for (int n = 0; n < 16; ++n) {
        h[n] = __expf(dv * An[n]) * h[n] + dx * BCsh[g + j][n];
        yv += h[n] * BCsh[g + j][16 + n];
      }
      ybase[(size_t)(g + j) * DI] = f2b(yv + Dv * xv);
      w[0] = w[1]; w[1] = w[2]; w[2] = w[3]; w[3] = nx[j];
    }
  }
}

// ---------------------------------------------------------------------------
extern "C" void kernel_launch(void* const* d_in, const int* in_sizes, int n_in,
                              void* d_out, int out_size, void* d_ws, size_t ws_size,
                              hipStream_t stream)
{
  const float* x       = (const float*)d_in[0];
  const float* Wis     = (const float*)d_in[1];
  const float* Wig     = (const float*)d_in[2];
  const float* conv_w  = (const float*)d_in[3];
  const float* conv_b  = (const float*)d_in[4];
  const float* conv_wb = (const float*)d_in[5];
  const float* conv_bb = (const float*)d_in[6];
  const float* W_dt    = (const float*)d_in[7];
  const float* W_B     = (const float*)d_in[8];
  const float* W_C     = (const float*)d_in[9];
  const float* dtW     = (const float*)d_in[10];
  const float* dtb     = (const float*)d_in[11];
  const float* A_log   = (const float*)d_in[12];
  const float* Dp      = (const float*)d_in[13];
  const float* W_dt_b  = (const float*)d_in[14];
  const float* W_B_b   = (const float*)d_in[15];
  const float* W_C_b   = (const float*)d_in[16];
  const float* dtW_b   = (const float*)d_in[17];
  const float* dtb_b   = (const float*)d_in[18];
  const float* A_log_b = (const float*)d_in[19];
  const float* Dp_b    = (const float*)d_in[20];
  const float* W_out   = (const float*)d_in[21];

  char* ws = (char*)d_ws;
  size_t off = 0;
  auto alloc = [&](size_t bytes) -> char* {
    char* p = ws + off; off += (bytes + 255) & ~(size_t)255; return p;
  };
  u16*   xb    = (u16*)alloc((size_t)ML * DM * 2);
  u16*   wisb  = (u16*)alloc((size_t)DI * DM * 2);
  u16*   wigb  = (u16*)alloc((size_t)DI * DM * 2);
  u16*   woutb = (u16*)alloc((size_t)DM * DI * 2);
  u16*   xsg = (u16*)alloc((size_t)ML * 3072 * 2);     // [xs | silu(z)]
  u16*   wcf = (u16*)alloc((size_t)128 * DI * 2);      // [B|C|W_dt|0]
  u16*   wcb = (u16*)alloc((size_t)128 * DI * 2);
  u16*   dtwf = (u16*)alloc((size_t)DI * 64 * 2);      // dtW bf16 K-padded
  u16*   dtwb = (u16*)alloc((size_t)DI * 64 * 2);
  float* pf  = (float*)alloc((size_t)ML * 32 * 4);     // [B|C] fp32, ld 32
  float* pb  = (float*)alloc((size_t)ML * 32 * 4);
  u16*   dtlf = (u16*)alloc((size_t)ML * 64 * 2);      // dt_low bf16, ld 64
  u16*   dtlb = (u16*)alloc((size_t)ML * 64 * 2);
  float* df  = (float*)alloc((size_t)ML * DI * 4);     // delta (softplus'd)
  float* db  = (float*)alloc((size_t)ML * DI * 4);
  u16*   yf  = (u16*)alloc((size_t)ML * DI * 2);
  u16*   ybr = (u16*)alloc((size_t)ML * DI * 2);       // reversed space
  float* sdl = (float*)alloc((size_t)2 * BB * NSEG * DI * 4);
  float* bs  = (float*)alloc((size_t)2 * BB * NSEG * DI * 16 * 4);

  // 1. fp32->bf16 conversion + weight packing
  const int conv_total = SEG_X + 3 * SEG_W + 2 * SEG_CAT + 2 * SEG_DTW;
  convert_kernel<<<(conv_total + 255) / 256, 256, 0, stream>>>(
      (const float4*)x, (const float4*)Wis, (const float4*)Wig, (const float4*)W_out,
      W_B, W_C, W_dt, W_B_b, W_C_b, W_dt_b, dtW, dtW_b,
      (u16x4_t*)xb, (u16x4_t*)wisb, (u16x4_t*)wigb, (u16x4_t*)woutb,
      (u16x4_t*)wcf, (u16x4_t*)wcb, (u16x4_t*)dtwf, (u16x4_t*)dtwb);

  // 2. in-proj: [xs | silu(z)] = x @ [Wis; Wig]^T
  gemm_bt<<<dim3(3072 / 128, ML / 128, 1), 256, 0, stream>>>(
      xb, wisb, wigb, DI, xsg, ML, 3072, DM, 3072, 0,
      nullptr, nullptr, nullptr, nullptr, nullptr);

  // 3. proj GEMM with fused conv+silu A-staging (both dirs)
  gemm_projconv<<<dim3(1, ML / 128, 2), 256, 0, stream>>>(
      xsg, wcf, wcb, conv_w, conv_b, conv_wb, conv_bb, pf, pb, dtlf, dtlb);

  // 4. delta GEMM: delta = softplus(dt_low @ dtW^T + dtb), K=64, fp32 out
  gemm_bt<<<dim3(DI / 128, ML / 128, 2), 256, 0, stream>>>(
      dtlf, dtwf, nullptr, 1 << 30, df, ML, DI, 64, DI, 6,
      dtlb, dtwb, db, dtb, dtb_b);

  // 5. segmented scan (conv inlined): summaries -> carries -> apply
  scan_sum<<<dim3(DI / 256, BB, 2 * NSEG), 256, 0, stream>>>(
      xsg, conv_w, conv_b, conv_wb, conv_bb, df, db, pf, pb,
      A_log, A_log_b, sdl, bs);
  scan_carry<<<(2 * BB * DI * 16) / 256, 256, 0, stream>>>(
      A_log, A_log_b, sdl, bs);
  scan_apply<<<dim3(DI / 256, BB, 2 * NSEG), 256, 0, stream>>>(
      xsg, conv_w, conv_b, conv_wb, conv_bb, df, db, pf, pb,
      A_log, A_log_b, Dp, Dp_b, bs, yf, ybr);

  // 6. out-proj with fused gated combine in A-staging
  gemm_out<<<dim3(DM / 128, ML / 128, 1), 256, 0, stream>>>(
      yf, ybr, xsg, woutb, (float*)d_out);
}

// Round 14
// 307.709 us; speedup vs baseline: 1.3823x; 1.3823x over previous
//
#include <hip/hip_runtime.h>
#include <hip/hip_bf16.h>
#include <stdint.h>

// Problem dims (fixed by the reference)
#define DM 768
#define DI 1536
#define DSTATE 16
#define RNK 48
#define BB 2
#define LL 1024
#define ML (BB * LL)  // 2048 rows (b*l flattened)

// segmented scan config
#define NSEG 32
#define SEGL (LL / NSEG)   // 32

typedef unsigned short u16;
typedef __bf16 bf16x8 __attribute__((ext_vector_type(8)));
typedef float f32x4 __attribute__((ext_vector_type(4)));

struct __align__(8) u16x4_t { u16 x, y, z, w; };

__device__ __forceinline__ float b2f(u16 u) {
  union { uint32_t i; float f; } v; v.i = ((uint32_t)u) << 16; return v.f;
}
__device__ __forceinline__ u16 f2b(float f) {
  union { float f; uint32_t i; } v; v.f = f;
  uint32_t r = v.i + 0x7FFFu + ((v.i >> 16) & 1u);  // RNE
  return (u16)(r >> 16);
}
__device__ __forceinline__ float silu_f(float x) { return x / (1.f + __expf(-x)); }
__device__ __forceinline__ float softplus_f(float s) {
  return fmaxf(s, 0.f) + __logf(1.f + __expf(-fabsf(s)));
}
__device__ __forceinline__ u16x4_t cvt4(float4 v) {
  u16x4_t o; o.x = f2b(v.x); o.y = f2b(v.y); o.z = f2b(v.z); o.w = f2b(v.w); return o;
}

// ---------------------------------------------------------------------------
// Fused fp32->bf16 conversion of GEMM operands + small-weight packing.
// wcat (128x1536): rows 0..15=W_B, 16..31=W_C, 32..79=W_dt, 80..127=0
// dtWb (1536x64):  cols 0..47=dtW row, 48..63=0
// ---------------------------------------------------------------------------
#define SEG_X    (ML * DM / 4)
#define SEG_W    (DI * DM / 4)
#define SEG_CAT  (128 * DI / 4)
#define SEG_DTW  (DI * 64 / 4)
__global__ __launch_bounds__(256) void convert_kernel(
    const float4* __restrict__ x, const float4* __restrict__ wis,
    const float4* __restrict__ wig, const float4* __restrict__ wout,
    const float* __restrict__ W_B, const float* __restrict__ W_C,
    const float* __restrict__ W_dt,
    const float* __restrict__ W_B_b, const float* __restrict__ W_C_b,
    const float* __restrict__ W_dt_b,
    const float* __restrict__ dtW, const float* __restrict__ dtW_b,
    u16x4_t* __restrict__ xb, u16x4_t* __restrict__ wisb,
    u16x4_t* __restrict__ wigb, u16x4_t* __restrict__ woutb,
    u16x4_t* __restrict__ wcf, u16x4_t* __restrict__ wcb,
    u16x4_t* __restrict__ dtwf, u16x4_t* __restrict__ dtwb)
{
  int idx = blockIdx.x * 256 + threadIdx.x;
  if (idx < SEG_X) { xb[idx] = cvt4(x[idx]); return; }
  idx -= SEG_X;
  if (idx < SEG_W) { wisb[idx] = cvt4(wis[idx]); return; }
  idx -= SEG_W;
  if (idx < SEG_W) { wigb[idx] = cvt4(wig[idx]); return; }
  idx -= SEG_W;
  if (idx < SEG_W) { woutb[idx] = cvt4(wout[idx]); return; }
  idx -= SEG_W;
  if (idx < 2 * SEG_CAT) {
    int dir = idx / SEG_CAT;
    int rem = idx % SEG_CAT;
    int row = rem / (DI / 4), k4 = rem % (DI / 4);
    const float* src = nullptr;
    if (row < 16)      src = (dir ? W_B_b  : W_B)  + (size_t)row * DI + k4 * 4;
    else if (row < 32) src = (dir ? W_C_b  : W_C)  + (size_t)(row - 16) * DI + k4 * 4;
    else if (row < 80) src = (dir ? W_dt_b : W_dt) + (size_t)(row - 32) * DI + k4 * 4;
    u16x4_t o;
    if (src) o = cvt4(*(const float4*)src);
    else { o.x = 0; o.y = 0; o.z = 0; o.w = 0; }
    (dir ? wcb : wcf)[rem] = o;
    return;
  }
  idx -= 2 * SEG_CAT;
  int dir = idx / SEG_DTW;
  int rem = idx % SEG_DTW;
  int d = rem / 16, r4 = rem % 16;
  const float* Dw = dir ? dtW_b : dtW;
  u16x4_t o;
  if (r4 < 12) o = cvt4(*(const float4*)(Dw + (size_t)d * RNK + r4 * 4));
  else { o.x = 0; o.y = 0; o.z = 0; o.w = 0; }
  (dir ? dtwb : dtwf)[rem] = o;
}

// ---------------------------------------------------------------------------
// Generic bf16 GEMM: C = A (MxK) @ B^T (NxK). 128x128 tile, 4 waves,
// 16x16x32 MFMA, reg double-buffer pipeline (round 9).
// epi: 0 bf16 (dual-B silu via B1/Nsplit) | 2 fp32 |
//      5 proj: col<32 fp32->Cout(ld 32), 32<=col<96 bf16->Caux(ld 64), else skip
//      6 delta: fp32 softplus(acc + ebias[col]) -> Cout (ld ldc)
// blockIdx.z==1 switches to (A2,B2,C2,Caux2,ebias2).
// NOTE r13: do NOT fuse conv into this kernel's staging — the proj grid is
// only 32 blocks; moving conv's 3.1M-elem workload there measured 152us at
// 1.4% occupancy (round 13). Keep conv standalone.
// ---------------------------------------------------------------------------
__global__ __launch_bounds__(256) void gemm_bt(
    const u16* __restrict__ A, const u16* __restrict__ B0,
    const u16* __restrict__ B1, int Nsplit,
    void* __restrict__ Cout, int M, int N, int K, int ldc, int epi,
    const u16* __restrict__ A2, const u16* __restrict__ B2,
    void* __restrict__ C2,
    u16* __restrict__ Caux, u16* __restrict__ Caux2,
    const float* __restrict__ ebias, const float* __restrict__ ebias2)
{
  if (blockIdx.z) { A = A2; B0 = B2; Cout = C2; Caux = Caux2; ebias = ebias2; }
  __shared__ alignas(16) u16 As[128 * 32];
  __shared__ alignas(16) u16 Bs[128 * 32];
  const int tid = threadIdx.x;
  const int wave = tid >> 6, lane = tid & 63;
  const int bm = blockIdx.y * 128;
  const int bn = blockIdx.x * 128;

  const u16* Bmat = B0;
  int ncol0 = bn;
  int epi_l = epi;
  if (B1 != nullptr && bn >= Nsplit) { Bmat = B1; ncol0 = bn - Nsplit; epi_l = 1; }

  const int c0 = tid, c1 = tid + 256;
  const u16* gA0 = A + (size_t)(bm + (c0 >> 2)) * K + (c0 & 3) * 8;
  const u16* gA1 = A + (size_t)(bm + (c1 >> 2)) * K + (c1 & 3) * 8;
  const u16* gB0 = Bmat + (size_t)(ncol0 + (c0 >> 2)) * K + (c0 & 3) * 8;
  const u16* gB1 = Bmat + (size_t)(ncol0 + (c1 >> 2)) * K + (c1 & 3) * 8;
  uint4* lA0 = (uint4*)&As[c0 * 8]; uint4* lA1 = (uint4*)&As[c1 * 8];
  uint4* lB0 = (uint4*)&Bs[c0 * 8]; uint4* lB1 = (uint4*)&Bs[c1 * 8];

  const int wm = (wave & 1) * 64, wn = (wave >> 1) * 64;
  const int rl = lane & 15, q = lane >> 4;

  f32x4 acc[4][4];
#pragma unroll
  for (int i = 0; i < 4; ++i)
#pragma unroll
    for (int j = 0; j < 4; ++j) acc[i][j] = (f32x4){0.f, 0.f, 0.f, 0.f};

  const bf16x8* AsV = (const bf16x8*)As;
  const bf16x8* BsV = (const bf16x8*)Bs;

  uint4 ra0 = *(const uint4*)(gA0);
  uint4 ra1 = *(const uint4*)(gA1);
  uint4 rb0 = *(const uint4*)(gB0);
  uint4 rb1 = *(const uint4*)(gB1);

  for (int k0 = 0; k0 < K; k0 += 32) {
    *lA0 = ra0; *lA1 = ra1; *lB0 = rb0; *lB1 = rb1;
    __syncthreads();
    if (k0 + 32 < K) {
      ra0 = *(const uint4*)(gA0 + k0 + 32);
      ra1 = *(const uint4*)(gA1 + k0 + 32);
      rb0 = *(const uint4*)(gB0 + k0 + 32);
      rb1 = *(const uint4*)(gB1 + k0 + 32);
    }
    bf16x8 af[4], bfv[4];
#pragma unroll
    for (int s = 0; s < 4; ++s) {
      af[s]  = AsV[(wm + s * 16 + rl) * 4 + q];
      bfv[s] = BsV[(wn + s * 16 + rl) * 4 + q];
    }
#pragma unroll
    for (int i = 0; i < 4; ++i)
#pragma unroll
      for (int j = 0; j < 4; ++j)
        acc[i][j] = __builtin_amdgcn_mfma_f32_16x16x32_bf16(af[i], bfv[j], acc[i][j], 0, 0, 0);
    __syncthreads();
  }

  // epilogue: C/D layout col=lane&15, row=(lane>>4)*4+reg
#pragma unroll
  for (int i = 0; i < 4; ++i) {
#pragma unroll
    for (int j = 0; j < 4; ++j) {
#pragma unroll
      for (int r = 0; r < 4; ++r) {
        int row = bm + wm + i * 16 + q * 4 + r;
        int col = bn + wn + j * 16 + rl;
        float v = acc[i][j][r];
        if (epi_l == 1) v = silu_f(v);
        if (epi == 5) {
          if (col < 32)      ((float*)Cout)[(size_t)row * 32 + col] = v;
          else if (col < 96) Caux[(size_t)row * 64 + (col - 32)] = f2b(v);
        } else if (epi == 6) {
          ((float*)Cout)[(size_t)row * ldc + col] = softplus_f(v + ebias[col]);
        } else if (epi == 2) {
          ((float*)Cout)[(size_t)row * ldc + col] = v;
        } else {
          ((u16*)Cout)[(size_t)row * ldc + col] = f2b(v);
        }
      }
    }
  }
}

// ---------------------------------------------------------------------------
// Causal depthwise conv (K=4, fp32 weights) + SiLU, fwd + reversed.
// 12288 blocks — keep standalone (see r13 note above).
// ---------------------------------------------------------------------------
__global__ void conv_kernel(
    const u16* __restrict__ xsg,
    const float* __restrict__ cw, const float* __restrict__ cb,
    const float* __restrict__ cwb, const float* __restrict__ cbb,
    u16* __restrict__ xc, u16* __restrict__ xcb)
{
  int idx = blockIdx.x * 256 + threadIdx.x;      // over ML*DI
  int d = idx % DI;
  int row = idx / DI;
  int l = row % LL, b = row / LL;
  const u16* base = xsg + (size_t)b * LL * 3072 + d;

  float4 wf = *(const float4*)(cw + d * 4);
  float4 wb = *(const float4*)(cwb + d * 4);
  float wfk[4] = {wf.x, wf.y, wf.z, wf.w};
  float wbk[4] = {wb.x, wb.y, wb.z, wb.w};

  float accf = cb[d];
  float accb = cbb[d];
#pragma unroll
  for (int k = 0; k < 4; ++k) {
    int ls = l - 3 + k;
    if (ls >= 0) {
      accf += wfk[k] * b2f(base[(size_t)ls * 3072]);
      accb += wbk[k] * b2f(base[(size_t)(LL - 1 - ls) * 3072]);
    }
  }
  xc[idx]  = f2b(silu_f(accf));
  xcb[idx] = f2b(silu_f(accb));
}

// ---------------------------------------------------------------------------
// Out-proj GEMM with FUSED gated combine in A-staging (validated round 13):
// A[row,k] = 0.5*(yf[row,k] + ybr[rev(row),k]) * gate[row,k]; fp32 out.
// ---------------------------------------------------------------------------
__global__ __launch_bounds__(256) void gemm_out(
    const u16* __restrict__ yf, const u16* __restrict__ ybr,
    const u16* __restrict__ xsg, const u16* __restrict__ Bw,
    float* __restrict__ out)
{
  __shared__ alignas(16) u16 As[128 * 32];
  __shared__ alignas(16) u16 Bs[128 * 32];
  const int tid = threadIdx.x;
  const int wave = tid >> 6, lane = tid & 63;
  const int bm = blockIdx.y * 128;
  const int bn = blockIdx.x * 128;

  const int c0 = tid, c1 = tid + 256;
  int r0 = bm + (c0 >> 2), r1 = bm + (c1 >> 2);
  int dc0 = (c0 & 3) * 8, dc1 = (c1 & 3) * 8;
  int rr0 = (r0 / LL) * LL + (LL - 1 - (r0 % LL));
  int rr1 = (r1 / LL) * LL + (LL - 1 - (r1 % LL));
  const u16* gy0 = yf + (size_t)r0 * DI + dc0;
  const u16* gy1 = yf + (size_t)r1 * DI + dc1;
  const u16* gr0 = ybr + (size_t)rr0 * DI + dc0;
  const u16* gr1 = ybr + (size_t)rr1 * DI + dc1;
  const u16* gg0 = xsg + (size_t)r0 * 3072 + DI + dc0;
  const u16* gg1 = xsg + (size_t)r1 * 3072 + DI + dc1;
  const u16* gB0 = Bw + (size_t)(bn + (c0 >> 2)) * DI + dc0;
  const u16* gB1 = Bw + (size_t)(bn + (c1 >> 2)) * DI + dc1;
  uint4* lA0 = (uint4*)&As[c0 * 8]; uint4* lA1 = (uint4*)&As[c1 * 8];
  uint4* lB0 = (uint4*)&Bs[c0 * 8]; uint4* lB1 = (uint4*)&Bs[c1 * 8];

  const int wm = (wave & 1) * 64, wn = (wave >> 1) * 64;
  const int rl = lane & 15, q = lane >> 4;

  f32x4 acc[4][4];
#pragma unroll
  for (int i = 0; i < 4; ++i)
#pragma unroll
    for (int j = 0; j < 4; ++j) acc[i][j] = (f32x4){0.f, 0.f, 0.f, 0.f};

  const bf16x8* AsV = (const bf16x8*)As;
  const bf16x8* BsV = (const bf16x8*)Bs;

  uint4 ry0 = *(const uint4*)gy0, ry1 = *(const uint4*)gy1;
  uint4 rr0v = *(const uint4*)gr0, rr1v = *(const uint4*)gr1;
  uint4 rg0 = *(const uint4*)gg0, rg1 = *(const uint4*)gg1;
  uint4 rb0 = *(const uint4*)gB0, rb1 = *(const uint4*)gB1;

  for (int k0 = 0; k0 < DI; k0 += 32) {
    {
      const u16* yp0 = (const u16*)&ry0; const u16* bp0 = (const u16*)&rr0v;
      const u16* gp0 = (const u16*)&rg0;
      const u16* yp1 = (const u16*)&ry1; const u16* bp1 = (const u16*)&rr1v;
      const u16* gp1 = (const u16*)&rg1;
      u16 o0[8], o1[8];
#pragma unroll
      for (int e = 0; e < 8; ++e) {
        o0[e] = f2b(0.5f * (b2f(yp0[e]) + b2f(bp0[e])) * b2f(gp0[e]));
        o1[e] = f2b(0.5f * (b2f(yp1[e]) + b2f(bp1[e])) * b2f(gp1[e]));
      }
      *lA0 = *(const uint4*)o0;
      *lA1 = *(const uint4*)o1;
    }
    *lB0 = rb0; *lB1 = rb1;
    __syncthreads();
    if (k0 + 32 < DI) {
      ry0 = *(const uint4*)(gy0 + k0 + 32); ry1 = *(const uint4*)(gy1 + k0 + 32);
      rr0v = *(const uint4*)(gr0 + k0 + 32); rr1v = *(const uint4*)(gr1 + k0 + 32);
      rg0 = *(const uint4*)(gg0 + k0 + 32); rg1 = *(const uint4*)(gg1 + k0 + 32);
      rb0 = *(const uint4*)(gB0 + k0 + 32); rb1 = *(const uint4*)(gB1 + k0 + 32);
    }
    bf16x8 af[4], bfv[4];
#pragma unroll
    for (int s = 0; s < 4; ++s) {
      af[s]  = AsV[(wm + s * 16 + rl) * 4 + q];
      bfv[s] = BsV[(wn + s * 16 + rl) * 4 + q];
    }
#pragma unroll
    for (int i = 0; i < 4; ++i)
#pragma unroll
      for (int j = 0; j < 4; ++j)
        acc[i][j] = __builtin_amdgcn_mfma_f32_16x16x32_bf16(af[i], bfv[j], acc[i][j], 0, 0, 0);
    __syncthreads();
  }

#pragma unroll
  for (int i = 0; i < 4; ++i) {
#pragma unroll
    for (int j = 0; j < 4; ++j) {
#pragma unroll
      for (int r = 0; r < 4; ++r) {
        int row = bm + wm + i * 16 + q * 4 + r;
        int col = bn + wn + j * 16 + rl;
        out[(size_t)row * DM + col] = acc[i][j][r];
      }
    }
  }
}

// ---------------------------------------------------------------------------
// Segmented scan, phase A: per (dir,b,seg,d) compute Sdelta and local
// end-state h_local[16] (h_in=0). delta precomputed (softplus in delta-GEMM
// epilogue). B from proj (ld 32, cols 0..15).
// ---------------------------------------------------------------------------
__global__ __launch_bounds__(256) void scan_sum(
    const float* __restrict__ df, const float* __restrict__ db,
    const u16* __restrict__ xcf, const u16* __restrict__ xcb,
    const float* __restrict__ pf, const float* __restrict__ pb,
    const float* __restrict__ A_log, const float* __restrict__ A_log_b,
    float* __restrict__ sdl, float* __restrict__ bs)
{
  const int dir = blockIdx.z / NSEG, seg = blockIdx.z % NSEG;
  const float* delta = dir ? db : df;
  const u16* xc = dir ? xcb : xcf;
  const float* proj = dir ? pb : pf;
  const float* Al = dir ? A_log_b : A_log;
  const int b = blockIdx.y;
  const int d = blockIdx.x * 256 + threadIdx.x;
  const int l0 = seg * SEGL;

  __shared__ float Bsh[SEGL][16];
  for (int i = threadIdx.x; i < SEGL * 16; i += 256) {
    int l = i >> 4, n = i & 15;
    Bsh[l][n] = proj[((size_t)b * LL + l0 + l) * 32 + n];
  }
  __syncthreads();

  float An[16];
#pragma unroll
  for (int n = 0; n < 16; ++n) An[n] = -__expf(Al[d * 16 + n]);

  float h[16];
#pragma unroll
  for (int n = 0; n < 16; ++n) h[n] = 0.f;
  float S = 0.f;

  const float* dbase = delta + ((size_t)b * LL + l0) * DI + d;
  const u16* xbase = xc + ((size_t)b * LL + l0) * DI + d;

  for (int g = 0; g < SEGL; g += 4) {
    float dl4[4], dx4[4];
#pragma unroll
    for (int j = 0; j < 4; ++j) {
      float dv = dbase[(size_t)(g + j) * DI];
      float xv = b2f(xbase[(size_t)(g + j) * DI]);
      dl4[j] = dv; dx4[j] = dv * xv;
    }
#pragma unroll
    for (int j = 0; j < 4; ++j) {
      S += dl4[j];
#pragma unroll
      for (int n = 0; n < 16; ++n)
        h[n] = __expf(dl4[j] * An[n]) * h[n] + dx4[j] * Bsh[g + j][n];
    }
  }

  size_t base = (((size_t)dir * BB + b) * NSEG + seg) * DI + d;
  sdl[base] = S;
#pragma unroll
  for (int n = 0; n < 16; ++n) bs[base * 16 + n] = h[n];
}

// ---------------------------------------------------------------------------
// Phase B: compose segment summaries into carry-ins (bs overwritten in place).
// ---------------------------------------------------------------------------
__global__ __launch_bounds__(256) void scan_carry(
    const float* __restrict__ A_log, const float* __restrict__ A_log_b,
    const float* __restrict__ sdl, float* __restrict__ bs)
{
  int idx = blockIdx.x * 256 + threadIdx.x;   // over 2*BB*DI*16
  int n = idx & 15;
  int t = idx >> 4;
  int d = t % DI;
  int b = (t / DI) % BB;
  int dir = t / (DI * BB);
  const float* Al = dir ? A_log_b : A_log;
  float An = -__expf(Al[d * 16 + n]);
  float h = 0.f;
  for (int s = 0; s < NSEG; ++s) {
    size_t base = (((size_t)dir * BB + b) * NSEG + s) * DI + d;
    float S = sdl[base];
    float bv = bs[base * 16 + n];
    bs[base * 16 + n] = h;
    h = __expf(S * An) * h + bv;
  }
}

// ---------------------------------------------------------------------------
// Phase C: redo recurrence from carry-in, compute y. B/C from proj ld 32.
// ---------------------------------------------------------------------------
__global__ __launch_bounds__(256) void scan_apply(
    const float* __restrict__ df, const float* __restrict__ db,
    const u16* __restrict__ xcf, const u16* __restrict__ xcb,
    const float* __restrict__ pf, const float* __restrict__ pb,
    const float* __restrict__ A_log, const float* __restrict__ A_log_b,
    const float* __restrict__ Dp, const float* __restrict__ Dp_b,
    const float* __restrict__ bs,
    u16* __restrict__ y_f, u16* __restrict__ y_b)
{
  const int dir = blockIdx.z / NSEG, seg = blockIdx.z % NSEG;
  const float* delta = dir ? db : df;
  const u16* xc = dir ? xcb : xcf;
  const float* proj = dir ? pb : pf;
  const float* Al = dir ? A_log_b : A_log;
  const float* Dpp = dir ? Dp_b : Dp;
  u16* y = dir ? y_b : y_f;
  const int b = blockIdx.y;
  const int d = blockIdx.x * 256 + threadIdx.x;
  const int l0 = seg * SEGL;

  __shared__ float BCsh[SEGL][32];            // [l][0:16)=B, [16:32)=C
  for (int i = threadIdx.x; i < SEGL * 32; i += 256) {
    int l = i >> 5, j = i & 31;
    BCsh[l][j] = proj[((size_t)b * LL + l0 + l) * 32 + j];
  }
  __syncthreads();

  float An[16];
#pragma unroll
  for (int n = 0; n < 16; ++n) An[n] = -__expf(Al[d * 16 + n]);
  const float Dv = Dpp[d];

  float h[16];
  size_t cbase = (((size_t)dir * BB + b) * NSEG + seg) * DI + d;
#pragma unroll
  for (int n = 0; n < 16; ++n) h[n] = bs[cbase * 16 + n];

  const float* dbase = delta + ((size_t)b * LL + l0) * DI + d;
  const u16* xbase = xc + ((size_t)b * LL + l0) * DI + d;
  u16* ybase = y + ((size_t)b * LL + l0) * DI + d;

  for (int g = 0; g < SEGL; g += 4) {
    float dl4[4], xv4[4];
#pragma unroll
    for (int j = 0; j < 4; ++j) {
      dl4[j] = dbase[(size_t)(g + j) * DI];
      xv4[j] = b2f(xbase[(size_t)(g + j) * DI]);
    }
#pragma unroll
    for (int j = 0; j < 4; ++j) {
      float dx = dl4[j] * xv4[j];
      float yv = 0.f;
#pragma unroll
      for (int n = 0; n < 16; ++n) {
        h[n] = __expf(dl4[j] * An[n]) * h[n] + dx * BCsh[g + j][n];
        yv += h[n] * BCsh[g + j][16 + n];
      }
      ybase[(size_t)(g + j) * DI] = f2b(yv + Dv * xv4[j]);
    }
  }
}

// ---------------------------------------------------------------------------
extern "C" void kernel_launch(void* const* d_in, const int* in_sizes, int n_in,
                              void* d_out, int out_size, void* d_ws, size_t ws_size,
                              hipStream_t stream)
{
  const float* x       = (const float*)d_in[0];
  const float* Wis     = (const float*)d_in[1];
  const float* Wig     = (const float*)d_in[2];
  const float* conv_w  = (const float*)d_in[3];
  const float* conv_b  = (const float*)d_in[4];
  const float* conv_wb = (const float*)d_in[5];
  const float* conv_bb = (const float*)d_in[6];
  const float* W_dt    = (const float*)d_in[7];
  const float* W_B     = (const float*)d_in[8];
  const float* W_C     = (const float*)d_in[9];
  const float* dtW     = (const float*)d_in[10];
  const float* dtb     = (const float*)d_in[11];
  const float* A_log   = (const float*)d_in[12];
  const float* Dp      = (const float*)d_in[13];
  const float* W_dt_b  = (const float*)d_in[14];
  const float* W_B_b   = (const float*)d_in[15];
  const float* W_C_b   = (const float*)d_in[16];
  const float* dtW_b   = (const float*)d_in[17];
  const float* dtb_b   = (const float*)d_in[18];
  const float* A_log_b = (const float*)d_in[19];
  const float* Dp_b    = (const float*)d_in[20];
  const float* W_out   = (const float*)d_in[21];

  char* ws = (char*)d_ws;
  size_t off = 0;
  auto alloc = [&](size_t bytes) -> char* {
    char* p = ws + off; off += (bytes + 255) & ~(size_t)255; return p;
  };
  u16*   xb    = (u16*)alloc((size_t)ML * DM * 2);
  u16*   wisb  = (u16*)alloc((size_t)DI * DM * 2);
  u16*   wigb  = (u16*)alloc((size_t)DI * DM * 2);
  u16*   woutb = (u16*)alloc((size_t)DM * DI * 2);
  u16*   xsg = (u16*)alloc((size_t)ML * 3072 * 2);     // [xs | silu(z)]
  u16*   xc  = (u16*)alloc((size_t)ML * DI * 2);
  u16*   xcb = (u16*)alloc((size_t)ML * DI * 2);       // reversed space
  u16*   wcf = (u16*)alloc((size_t)128 * DI * 2);      // [B|C|W_dt|0]
  u16*   wcb = (u16*)alloc((size_t)128 * DI * 2);
  u16*   dtwf = (u16*)alloc((size_t)DI * 64 * 2);      // dtW bf16 K-padded
  u16*   dtwb = (u16*)alloc((size_t)DI * 64 * 2);
  float* pf  = (float*)alloc((size_t)ML * 32 * 4);     // [B|C] fp32, ld 32
  float* pb  = (float*)alloc((size_t)ML * 32 * 4);
  u16*   dtlf = (u16*)alloc((size_t)ML * 64 * 2);      // dt_low bf16, ld 64
  u16*   dtlb = (u16*)alloc((size_t)ML * 64 * 2);
  float* df  = (float*)alloc((size_t)ML * DI * 4);     // delta (softplus'd)
  float* db  = (float*)alloc((size_t)ML * DI * 4);
  u16*   yf  = (u16*)alloc((size_t)ML * DI * 2);
  u16*   ybr = (u16*)alloc((size_t)ML * DI * 2);       // reversed space
  float* sdl = (float*)alloc((size_t)2 * BB * NSEG * DI * 4);
  float* bs  = (float*)alloc((size_t)2 * BB * NSEG * DI * 16 * 4);

  // 1. fp32->bf16 conversion + weight packing (wcat, dtWb)
  const int conv_total = SEG_X + 3 * SEG_W + 2 * SEG_CAT + 2 * SEG_DTW;
  convert_kernel<<<(conv_total + 255) / 256, 256, 0, stream>>>(
      (const float4*)x, (const float4*)Wis, (const float4*)Wig, (const float4*)W_out,
      W_B, W_C, W_dt, W_B_b, W_C_b, W_dt_b, dtW, dtW_b,
      (u16x4_t*)xb, (u16x4_t*)wisb, (u16x4_t*)wigb, (u16x4_t*)woutb,
      (u16x4_t*)wcf, (u16x4_t*)wcb, (u16x4_t*)dtwf, (u16x4_t*)dtwb);

  // 2. in-proj: [xs | silu(z)] = x @ [Wis; Wig]^T
  gemm_bt<<<dim3(3072 / 128, ML / 128, 1), 256, 0, stream>>>(
      xb, wisb, wigb, DI, xsg, ML, 3072, DM, 3072, 0,
      nullptr, nullptr, nullptr, nullptr, nullptr, nullptr, nullptr);

  // 3. causal conv + silu (fwd + reversed)
  conv_kernel<<<(ML * DI) / 256, 256, 0, stream>>>(
      xsg, conv_w, conv_b, conv_wb, conv_bb, xc, xcb);

  // 4. proj GEMMs: [B|C fp32 -> pf] + [dt_low bf16 -> dtl] = xc @ wcat^T
  gemm_bt<<<dim3(1, ML / 128, 2), 256, 0, stream>>>(
      xc, wcf, nullptr, 1 << 30, pf, ML, 128, DI, 32, 5,
      xcb, wcb, pb, dtlf, dtlb, nullptr, nullptr);

  // 5. delta GEMM: delta = softplus(dt_low @ dtW^T + dtb), K=64, fp32 out
  gemm_bt<<<dim3(DI / 128, ML / 128, 2), 256, 0, stream>>>(
      dtlf, dtwf, nullptr, 1 << 30, df, ML, DI, 64, DI, 6,
      dtlb, dtwb, db, nullptr, nullptr, dtb, dtb_b);

  // 6. segmented scan: summaries -> carries -> apply
  scan_sum<<<dim3(DI / 256, BB, 2 * NSEG), 256, 0, stream>>>(
      df, db, xc, xcb, pf, pb, A_log, A_log_b, sdl, bs);
  scan_carry<<<(2 * BB * DI * 16) / 256, 256, 0, stream>>>(
      A_log, A_log_b, sdl, bs);
  scan_apply<<<dim3(DI / 256, BB, 2 * NSEG), 256, 0, stream>>>(
      df, db, xc, xcb, pf, pb, A_log, A_log_b, Dp, Dp_b, bs, yf, ybr);

  // 7. out-proj with fused gated combine in A-staging
  gemm_out<<<dim3(DM / 128, ML / 128, 1), 256, 0, stream>>>(
      yf, ybr, xsg, woutb, (float*)d_out);
}

// Round 15
// 285.178 us; speedup vs baseline: 1.4915x; 1.0790x over previous
//
#include <hip/hip_runtime.h>
#include <hip/hip_bf16.h>
#include <stdint.h>

// Problem dims (fixed by the reference)
#define DM 768
#define DI 1536
#define DSTATE 16
#define RNK 48
#define BB 2
#define LL 1024
#define ML (BB * LL)  // 2048 rows (b*l flattened)

// segmented scan config
#define NSEG 32
#define SEGL (LL / NSEG)   // 32

typedef unsigned short u16;
typedef __bf16 bf16x8 __attribute__((ext_vector_type(8)));
typedef float f32x4 __attribute__((ext_vector_type(4)));

struct __align__(8) u16x4_t { u16 x, y, z, w; };

__device__ __forceinline__ float b2f(u16 u) {
  union { uint32_t i; float f; } v; v.i = ((uint32_t)u) << 16; return v.f;
}
__device__ __forceinline__ u16 f2b(float f) {
  union { float f; uint32_t i; } v; v.f = f;
  uint32_t r = v.i + 0x7FFFu + ((v.i >> 16) & 1u);  // RNE
  return (u16)(r >> 16);
}
__device__ __forceinline__ float silu_f(float x) { return x / (1.f + __expf(-x)); }
__device__ __forceinline__ float softplus_f(float s) {
  return fmaxf(s, 0.f) + __logf(1.f + __expf(-fabsf(s)));
}
__device__ __forceinline__ u16x4_t cvt4(float4 v) {
  u16x4_t o; o.x = f2b(v.x); o.y = f2b(v.y); o.z = f2b(v.z); o.w = f2b(v.w); return o;
}

// ---------------------------------------------------------------------------
// Fused fp32->bf16 conversion of GEMM operands + small-weight packing.
// wcat (128x1536): rows 0..15=W_B, 16..31=W_C, 32..79=W_dt, 80..127=0
// dtWb (1536x64):  cols 0..47=dtW row, 48..63=0
// ---------------------------------------------------------------------------
#define SEG_X    (ML * DM / 4)
#define SEG_W    (DI * DM / 4)
#define SEG_CAT  (128 * DI / 4)
#define SEG_DTW  (DI * 64 / 4)
__global__ __launch_bounds__(256) void convert_kernel(
    const float4* __restrict__ x, const float4* __restrict__ wis,
    const float4* __restrict__ wig, const float4* __restrict__ wout,
    const float* __restrict__ W_B, const float* __restrict__ W_C,
    const float* __restrict__ W_dt,
    const float* __restrict__ W_B_b, const float* __restrict__ W_C_b,
    const float* __restrict__ W_dt_b,
    const float* __restrict__ dtW, const float* __restrict__ dtW_b,
    u16x4_t* __restrict__ xb, u16x4_t* __restrict__ wisb,
    u16x4_t* __restrict__ wigb, u16x4_t* __restrict__ woutb,
    u16x4_t* __restrict__ wcf, u16x4_t* __restrict__ wcb,
    u16x4_t* __restrict__ dtwf, u16x4_t* __restrict__ dtwb)
{
  int idx = blockIdx.x * 256 + threadIdx.x;
  if (idx < SEG_X) { xb[idx] = cvt4(x[idx]); return; }
  idx -= SEG_X;
  if (idx < SEG_W) { wisb[idx] = cvt4(wis[idx]); return; }
  idx -= SEG_W;
  if (idx < SEG_W) { wigb[idx] = cvt4(wig[idx]); return; }
  idx -= SEG_W;
  if (idx < SEG_W) { woutb[idx] = cvt4(wout[idx]); return; }
  idx -= SEG_W;
  if (idx < 2 * SEG_CAT) {
    int dir = idx / SEG_CAT;
    int rem = idx % SEG_CAT;
    int row = rem / (DI / 4), k4 = rem % (DI / 4);
    const float* src = nullptr;
    if (row < 16)      src = (dir ? W_B_b  : W_B)  + (size_t)row * DI + k4 * 4;
    else if (row < 32) src = (dir ? W_C_b  : W_C)  + (size_t)(row - 16) * DI + k4 * 4;
    else if (row < 80) src = (dir ? W_dt_b : W_dt) + (size_t)(row - 32) * DI + k4 * 4;
    u16x4_t o;
    if (src) o = cvt4(*(const float4*)src);
    else { o.x = 0; o.y = 0; o.z = 0; o.w = 0; }
    (dir ? wcb : wcf)[rem] = o;
    return;
  }
  idx -= 2 * SEG_CAT;
  int dir = idx / SEG_DTW;
  int rem = idx % SEG_DTW;
  int d = rem / 16, r4 = rem % 16;
  const float* Dw = dir ? dtW_b : dtW;
  u16x4_t o;
  if (r4 < 12) o = cvt4(*(const float4*)(Dw + (size_t)d * RNK + r4 * 4));
  else { o.x = 0; o.y = 0; o.z = 0; o.w = 0; }
  (dir ? dtwb : dtwf)[rem] = o;
}

// ---------------------------------------------------------------------------
// Generic bf16 GEMM: C = A (MxK) @ B^T (NxK). 128x128 tile, 4 waves,
// 16x16x32 MFMA, reg double-buffer pipeline (round 9).
// epi: 0 bf16 (dual-B silu via B1/Nsplit) | 2 fp32 |
//      5 proj: col<32 fp32->Cout(ld 32), 32<=col<96 bf16->Caux(ld 64), else skip
//      6 delta: fp32 softplus(acc + ebias[col]) -> Cout (ld ldc)
// blockIdx.z==1 switches to (A2,B2,C2,Caux2,ebias2).
// r13/r14 lesson: never fuse elementwise stages into grid-starved GEMMs.
// ---------------------------------------------------------------------------
__global__ __launch_bounds__(256) void gemm_bt(
    const u16* __restrict__ A, const u16* __restrict__ B0,
    const u16* __restrict__ B1, int Nsplit,
    void* __restrict__ Cout, int M, int N, int K, int ldc, int epi,
    const u16* __restrict__ A2, const u16* __restrict__ B2,
    void* __restrict__ C2,
    u16* __restrict__ Caux, u16* __restrict__ Caux2,
    const float* __restrict__ ebias, const float* __restrict__ ebias2)
{
  if (blockIdx.z) { A = A2; B0 = B2; Cout = C2; Caux = Caux2; ebias = ebias2; }
  __shared__ alignas(16) u16 As[128 * 32];
  __shared__ alignas(16) u16 Bs[128 * 32];
  const int tid = threadIdx.x;
  const int wave = tid >> 6, lane = tid & 63;
  const int bm = blockIdx.y * 128;
  const int bn = blockIdx.x * 128;

  const u16* Bmat = B0;
  int ncol0 = bn;
  int epi_l = epi;
  if (B1 != nullptr && bn >= Nsplit) { Bmat = B1; ncol0 = bn - Nsplit; epi_l = 1; }

  const int c0 = tid, c1 = tid + 256;
  const u16* gA0 = A + (size_t)(bm + (c0 >> 2)) * K + (c0 & 3) * 8;
  const u16* gA1 = A + (size_t)(bm + (c1 >> 2)) * K + (c1 & 3) * 8;
  const u16* gB0 = Bmat + (size_t)(ncol0 + (c0 >> 2)) * K + (c0 & 3) * 8;
  const u16* gB1 = Bmat + (size_t)(ncol0 + (c1 >> 2)) * K + (c1 & 3) * 8;
  uint4* lA0 = (uint4*)&As[c0 * 8]; uint4* lA1 = (uint4*)&As[c1 * 8];
  uint4* lB0 = (uint4*)&Bs[c0 * 8]; uint4* lB1 = (uint4*)&Bs[c1 * 8];

  const int wm = (wave & 1) * 64, wn = (wave >> 1) * 64;
  const int rl = lane & 15, q = lane >> 4;

  f32x4 acc[4][4];
#pragma unroll
  for (int i = 0; i < 4; ++i)
#pragma unroll
    for (int j = 0; j < 4; ++j) acc[i][j] = (f32x4){0.f, 0.f, 0.f, 0.f};

  const bf16x8* AsV = (const bf16x8*)As;
  const bf16x8* BsV = (const bf16x8*)Bs;

  uint4 ra0 = *(const uint4*)(gA0);
  uint4 ra1 = *(const uint4*)(gA1);
  uint4 rb0 = *(const uint4*)(gB0);
  uint4 rb1 = *(const uint4*)(gB1);

  for (int k0 = 0; k0 < K; k0 += 32) {
    *lA0 = ra0; *lA1 = ra1; *lB0 = rb0; *lB1 = rb1;
    __syncthreads();
    if (k0 + 32 < K) {
      ra0 = *(const uint4*)(gA0 + k0 + 32);
      ra1 = *(const uint4*)(gA1 + k0 + 32);
      rb0 = *(const uint4*)(gB0 + k0 + 32);
      rb1 = *(const uint4*)(gB1 + k0 + 32);
    }
    bf16x8 af[4], bfv[4];
#pragma unroll
    for (int s = 0; s < 4; ++s) {
      af[s]  = AsV[(wm + s * 16 + rl) * 4 + q];
      bfv[s] = BsV[(wn + s * 16 + rl) * 4 + q];
    }
#pragma unroll
    for (int i = 0; i < 4; ++i)
#pragma unroll
      for (int j = 0; j < 4; ++j)
        acc[i][j] = __builtin_amdgcn_mfma_f32_16x16x32_bf16(af[i], bfv[j], acc[i][j], 0, 0, 0);
    __syncthreads();
  }

  // epilogue: C/D layout col=lane&15, row=(lane>>4)*4+reg
#pragma unroll
  for (int i = 0; i < 4; ++i) {
#pragma unroll
    for (int j = 0; j < 4; ++j) {
#pragma unroll
      for (int r = 0; r < 4; ++r) {
        int row = bm + wm + i * 16 + q * 4 + r;
        int col = bn + wn + j * 16 + rl;
        float v = acc[i][j][r];
        if (epi_l == 1) v = silu_f(v);
        if (epi == 5) {
          if (col < 32)      ((float*)Cout)[(size_t)row * 32 + col] = v;
          else if (col < 96) Caux[(size_t)row * 64 + (col - 32)] = f2b(v);
        } else if (epi == 6) {
          ((float*)Cout)[(size_t)row * ldc + col] = softplus_f(v + ebias[col]);
        } else if (epi == 2) {
          ((float*)Cout)[(size_t)row * ldc + col] = v;
        } else {
          ((u16*)Cout)[(size_t)row * ldc + col] = f2b(v);
        }
      }
    }
  }
}

// ---------------------------------------------------------------------------
// Out-proj GEMM, 64x64 tile / K-tile 64 (round 15): grid (12,32)=384 blocks
// vs 96 at 128-tile — fixes the 3.7%-occupancy latency exposure measured in
// r14 (48.8us). Wave w owns N-strip [16w,16w+16); LDS rows padded to 72
// (144B stride -> 2-way bank aliasing, free per m136). fp32 out.
// ---------------------------------------------------------------------------
__global__ __launch_bounds__(256) void gemm_out64(
    const u16* __restrict__ A, const u16* __restrict__ Bw,
    float* __restrict__ out)
{
  __shared__ alignas(16) u16 As[64 * 72];
  __shared__ alignas(16) u16 Bs[64 * 72];
  const int tid = threadIdx.x;
  const int wave = tid >> 6, lane = tid & 63;
  const int bm = blockIdx.y * 64;
  const int bn = blockIdx.x * 64;

  // staging: 512 chunks of 16B per operand; chunk c -> row c>>3, col (c&7)*8
  const int c0 = tid, c1 = tid + 256;
  const u16* gA0 = A + (size_t)(bm + (c0 >> 3)) * DI + (c0 & 7) * 8;
  const u16* gA1 = A + (size_t)(bm + (c1 >> 3)) * DI + (c1 & 7) * 8;
  const u16* gB0 = Bw + (size_t)(bn + (c0 >> 3)) * DI + (c0 & 7) * 8;
  const u16* gB1 = Bw + (size_t)(bn + (c1 >> 3)) * DI + (c1 & 7) * 8;
  uint4* lA0 = (uint4*)&As[(c0 >> 3) * 72 + (c0 & 7) * 8];
  uint4* lA1 = (uint4*)&As[(c1 >> 3) * 72 + (c1 & 7) * 8];
  uint4* lB0 = (uint4*)&Bs[(c0 >> 3) * 72 + (c0 & 7) * 8];
  uint4* lB1 = (uint4*)&Bs[(c1 >> 3) * 72 + (c1 & 7) * 8];

  const int rl = lane & 15, q = lane >> 4;

  f32x4 acc[4];
#pragma unroll
  for (int s = 0; s < 4; ++s) acc[s] = (f32x4){0.f, 0.f, 0.f, 0.f};

  uint4 ra0 = *(const uint4*)gA0, ra1 = *(const uint4*)gA1;
  uint4 rb0 = *(const uint4*)gB0, rb1 = *(const uint4*)gB1;

  for (int k0 = 0; k0 < DI; k0 += 64) {
    *lA0 = ra0; *lA1 = ra1; *lB0 = rb0; *lB1 = rb1;
    __syncthreads();
    if (k0 + 64 < DI) {
      ra0 = *(const uint4*)(gA0 + k0 + 64);
      ra1 = *(const uint4*)(gA1 + k0 + 64);
      rb0 = *(const uint4*)(gB0 + k0 + 64);
      rb1 = *(const uint4*)(gB1 + k0 + 64);
    }
    bf16x8 bf[2], af;
#pragma unroll
    for (int c = 0; c < 2; ++c)
      bf[c] = *(const bf16x8*)&Bs[(wave * 16 + rl) * 72 + c * 32 + q * 8];
#pragma unroll
    for (int s = 0; s < 4; ++s) {
#pragma unroll
      for (int c = 0; c < 2; ++c) {
        af = *(const bf16x8*)&As[(s * 16 + rl) * 72 + c * 32 + q * 8];
        acc[s] = __builtin_amdgcn_mfma_f32_16x16x32_bf16(af, bf[c], acc[s], 0, 0, 0);
      }
    }
    __syncthreads();
  }

#pragma unroll
  for (int s = 0; s < 4; ++s) {
#pragma unroll
    for (int r = 0; r < 4; ++r) {
      int row = bm + s * 16 + q * 4 + r;
      int col = bn + wave * 16 + rl;
      out[(size_t)row * DM + col] = acc[s][r];
    }
  }
}

// ---------------------------------------------------------------------------
// Causal depthwise conv (K=4, fp32 weights) + SiLU, fwd + reversed.
// 12288 blocks — keep standalone (r13).
// ---------------------------------------------------------------------------
__global__ void conv_kernel(
    const u16* __restrict__ xsg,
    const float* __restrict__ cw, const float* __restrict__ cb,
    const float* __restrict__ cwb, const float* __restrict__ cbb,
    u16* __restrict__ xc, u16* __restrict__ xcb)
{
  int idx = blockIdx.x * 256 + threadIdx.x;      // over ML*DI
  int d = idx % DI;
  int row = idx / DI;
  int l = row % LL, b = row / LL;
  const u16* base = xsg + (size_t)b * LL * 3072 + d;

  float4 wf = *(const float4*)(cw + d * 4);
  float4 wb = *(const float4*)(cwb + d * 4);
  float wfk[4] = {wf.x, wf.y, wf.z, wf.w};
  float wbk[4] = {wb.x, wb.y, wb.z, wb.w};

  float accf = cb[d];
  float accb = cbb[d];
#pragma unroll
  for (int k = 0; k < 4; ++k) {
    int ls = l - 3 + k;
    if (ls >= 0) {
      accf += wfk[k] * b2f(base[(size_t)ls * 3072]);
      accb += wbk[k] * b2f(base[(size_t)(LL - 1 - ls) * 3072]);
    }
  }
  xc[idx]  = f2b(silu_f(accf));
  xcb[idx] = f2b(silu_f(accb));
}

// ---------------------------------------------------------------------------
// y_comb[l] = 0.5 * silu(z[l]) * (y_f[l] + y_b_rev[L-1-l]); in-place over yf
// (r11-validated; 12288 blocks).
// ---------------------------------------------------------------------------
__global__ void combine_kernel(
    const u16* __restrict__ ybr, const u16* __restrict__ xsg, u16* yf)
{
  int idx = blockIdx.x * 256 + threadIdx.x;      // over ML*DI
  int d = idx % DI;
  int row = idx / DI;
  int l = row % LL, b = row / LL;
  float g = b2f(xsg[(size_t)row * 3072 + DI + d]);
  float vb = b2f(ybr[((size_t)b * LL + (LL - 1 - l)) * DI + d]);
  float v = 0.5f * (b2f(yf[idx]) + vb) * g;
  yf[idx] = f2b(v);
}

// ---------------------------------------------------------------------------
// Segmented scan, phase A: per (dir,b,seg,d) compute Sdelta and local
// end-state h_local[16] (h_in=0). delta precomputed (softplus in delta-GEMM
// epilogue). B from proj (ld 32, cols 0..15).
// ---------------------------------------------------------------------------
__global__ __launch_bounds__(256) void scan_sum(
    const float* __restrict__ df, const float* __restrict__ db,
    const u16* __restrict__ xcf, const u16* __restrict__ xcb,
    const float* __restrict__ pf, const float* __restrict__ pb,
    const float* __restrict__ A_log, const float* __restrict__ A_log_b,
    float* __restrict__ sdl, float* __restrict__ bs)
{
  const int dir = blockIdx.z / NSEG, seg = blockIdx.z % NSEG;
  const float* delta = dir ? db : df;
  const u16* xc = dir ? xcb : xcf;
  const float* proj = dir ? pb : pf;
  const float* Al = dir ? A_log_b : A_log;
  const int b = blockIdx.y;
  const int d = blockIdx.x * 256 + threadIdx.x;
  const int l0 = seg * SEGL;

  __shared__ float Bsh[SEGL][16];
  for (int i = threadIdx.x; i < SEGL * 16; i += 256) {
    int l = i >> 4, n = i & 15;
    Bsh[l][n] = proj[((size_t)b * LL + l0 + l) * 32 + n];
  }
  __syncthreads();

  float An[16];
#pragma unroll
  for (int n = 0; n < 16; ++n) An[n] = -__expf(Al[d * 16 + n]);

  float h[16];
#pragma unroll
  for (int n = 0; n < 16; ++n) h[n] = 0.f;
  float S = 0.f;

  const float* dbase = delta + ((size_t)b * LL + l0) * DI + d;
  const u16* xbase = xc + ((size_t)b * LL + l0) * DI + d;

  for (int g = 0; g < SEGL; g += 4) {
    float dl4[4], dx4[4];
#pragma unroll
    for (int j = 0; j < 4; ++j) {
      float dv = dbase[(size_t)(g + j) * DI];
      float xv = b2f(xbase[(size_t)(g + j) * DI]);
      dl4[j] = dv; dx4[j] = dv * xv;
    }
#pragma unroll
    for (int j = 0; j < 4; ++j) {
      S += dl4[j];
#pragma unroll
      for (int n = 0; n < 16; ++n)
        h[n] = __expf(dl4[j] * An[n]) * h[n] + dx4[j] * Bsh[g + j][n];
    }
  }

  size_t base = (((size_t)dir * BB + b) * NSEG + seg) * DI + d;
  sdl[base] = S;
#pragma unroll
  for (int n = 0; n < 16; ++n) bs[base * 16 + n] = h[n];
}

// ---------------------------------------------------------------------------
// Phase B: compose segment summaries into carry-ins (bs overwritten in place).
// ---------------------------------------------------------------------------
__global__ __launch_bounds__(256) void scan_carry(
    const float* __restrict__ A_log, const float* __restrict__ A_log_b,
    const float* __restrict__ sdl, float* __restrict__ bs)
{
  int idx = blockIdx.x * 256 + threadIdx.x;   // over 2*BB*DI*16
  int n = idx & 15;
  int t = idx >> 4;
  int d = t % DI;
  int b = (t / DI) % BB;
  int dir = t / (DI * BB);
  const float* Al = dir ? A_log_b : A_log;
  float An = -__expf(Al[d * 16 + n]);
  float h = 0.f;
  for (int s = 0; s < NSEG; ++s) {
    size_t base = (((size_t)dir * BB + b) * NSEG + s) * DI + d;
    float S = sdl[base];
    float bv = bs[base * 16 + n];
    bs[base * 16 + n] = h;
    h = __expf(S * An) * h + bv;
  }
}

// ---------------------------------------------------------------------------
// Phase C: redo recurrence from carry-in, compute y. B/C from proj ld 32.
// ---------------------------------------------------------------------------
__global__ __launch_bounds__(256) void scan_apply(
    const float* __restrict__ df, const float* __restrict__ db,
    const u16* __restrict__ xcf, const u16* __restrict__ xcb,
    const float* __restrict__ pf, const float* __restrict__ pb,
    const float* __restrict__ A_log, const float* __restrict__ A_log_b,
    const float* __restrict__ Dp, const float* __restrict__ Dp_b,
    const float* __restrict__ bs,
    u16* __restrict__ y_f, u16* __restrict__ y_b)
{
  const int dir = blockIdx.z / NSEG, seg = blockIdx.z % NSEG;
  const float* delta = dir ? db : df;
  const u16* xc = dir ? xcb : xcf;
  const float* proj = dir ? pb : pf;
  const float* Al = dir ? A_log_b : A_log;
  const float* Dpp = dir ? Dp_b : Dp;
  u16* y = dir ? y_b : y_f;
  const int b = blockIdx.y;
  const int d = blockIdx.x * 256 + threadIdx.x;
  const int l0 = seg * SEGL;

  __shared__ float BCsh[SEGL][32];            // [l][0:16)=B, [16:32)=C
  for (int i = threadIdx.x; i < SEGL * 32; i += 256) {
    int l = i >> 5, j = i & 31;
    BCsh[l][j] = proj[((size_t)b * LL + l0 + l) * 32 + j];
  }
  __syncthreads();

  float An[16];
#pragma unroll
  for (int n = 0; n < 16; ++n) An[n] = -__expf(Al[d * 16 + n]);
  const float Dv = Dpp[d];

  float h[16];
  size_t cbase = (((size_t)dir * BB + b) * NSEG + seg) * DI + d;
#pragma unroll
  for (int n = 0; n < 16; ++n) h[n] = bs[cbase * 16 + n];

  const float* dbase = delta + ((size_t)b * LL + l0) * DI + d;
  const u16* xbase = xc + ((size_t)b * LL + l0) * DI + d;
  u16* ybase = y + ((size_t)b * LL + l0) * DI + d;

  for (int g = 0; g < SEGL; g += 4) {
    float dl4[4], xv4[4];
#pragma unroll
    for (int j = 0; j < 4; ++j) {
      dl4[j] = dbase[(size_t)(g + j) * DI];
      xv4[j] = b2f(xbase[(size_t)(g + j) * DI]);
    }
#pragma unroll
    for (int j = 0; j < 4; ++j) {
      float dx = dl4[j] * xv4[j];
      float yv = 0.f;
#pragma unroll
      for (int n = 0; n < 16; ++n) {
        h[n] = __expf(dl4[j] * An[n]) * h[n] + dx * BCsh[g + j][n];
        yv += h[n] * BCsh[g + j][16 + n];
      }
      ybase[(size_t)(g + j) * DI] = f2b(yv + Dv * xv4[j]);
    }
  }
}

// ---------------------------------------------------------------------------
extern "C" void kernel_launch(void* const* d_in, const int* in_sizes, int n_in,
                              void* d_out, int out_size, void* d_ws, size_t ws_size,
                              hipStream_t stream)
{
  const float* x       = (const float*)d_in[0];
  const float* Wis     = (const float*)d_in[1];
  const float* Wig     = (const float*)d_in[2];
  const float* conv_w  = (const float*)d_in[3];
  const float* conv_b  = (const float*)d_in[4];
  const float* conv_wb = (const float*)d_in[5];
  const float* conv_bb = (const float*)d_in[6];
  const float* W_dt    = (const float*)d_in[7];
  const float* W_B     = (const float*)d_in[8];
  const float* W_C     = (const float*)d_in[9];
  const float* dtW     = (const float*)d_in[10];
  const float* dtb     = (const float*)d_in[11];
  const float* A_log   = (const float*)d_in[12];
  const float* Dp      = (const float*)d_in[13];
  const float* W_dt_b  = (const float*)d_in[14];
  const float* W_B_b   = (const float*)d_in[15];
  const float* W_C_b   = (const float*)d_in[16];
  const float* dtW_b   = (const float*)d_in[17];
  const float* dtb_b   = (const float*)d_in[18];
  const float* A_log_b = (const float*)d_in[19];
  const float* Dp_b    = (const float*)d_in[20];
  const float* W_out   = (const float*)d_in[21];

  char* ws = (char*)d_ws;
  size_t off = 0;
  auto alloc = [&](size_t bytes) -> char* {
    char* p = ws + off; off += (bytes + 255) & ~(size_t)255; return p;
  };
  u16*   xb    = (u16*)alloc((size_t)ML * DM * 2);
  u16*   wisb  = (u16*)alloc((size_t)DI * DM * 2);
  u16*   wigb  = (u16*)alloc((size_t)DI * DM * 2);
  u16*   woutb = (u16*)alloc((size_t)DM * DI * 2);
  u16*   xsg = (u16*)alloc((size_t)ML * 3072 * 2);     // [xs | silu(z)]
  u16*   xc  = (u16*)alloc((size_t)ML * DI * 2);
  u16*   xcb = (u16*)alloc((size_t)ML * DI * 2);       // reversed space
  u16*   wcf = (u16*)alloc((size_t)128 * DI * 2);      // [B|C|W_dt|0]
  u16*   wcb = (u16*)alloc((size_t)128 * DI * 2);
  u16*   dtwf = (u16*)alloc((size_t)DI * 64 * 2);      // dtW bf16 K-padded
  u16*   dtwb = (u16*)alloc((size_t)DI * 64 * 2);
  float* pf  = (float*)alloc((size_t)ML * 32 * 4);     // [B|C] fp32, ld 32
  float* pb  = (float*)alloc((size_t)ML * 32 * 4);
  u16*   dtlf = (u16*)alloc((size_t)ML * 64 * 2);      // dt_low bf16, ld 64
  u16*   dtlb = (u16*)alloc((size_t)ML * 64 * 2);
  float* df  = (float*)alloc((size_t)ML * DI * 4);     // delta (softplus'd)
  float* db  = (float*)alloc((size_t)ML * DI * 4);
  u16*   yf  = (u16*)alloc((size_t)ML * DI * 2);       // holds combined y after step 7
  u16*   ybr = (u16*)alloc((size_t)ML * DI * 2);       // reversed space
  float* sdl = (float*)alloc((size_t)2 * BB * NSEG * DI * 4);
  float* bs  = (float*)alloc((size_t)2 * BB * NSEG * DI * 16 * 4);

  // 1. fp32->bf16 conversion + weight packing (wcat, dtWb)
  const int conv_total = SEG_X + 3 * SEG_W + 2 * SEG_CAT + 2 * SEG_DTW;
  convert_kernel<<<(conv_total + 255) / 256, 256, 0, stream>>>(
      (const float4*)x, (const float4*)Wis, (const float4*)Wig, (const float4*)W_out,
      W_B, W_C, W_dt, W_B_b, W_C_b, W_dt_b, dtW, dtW_b,
      (u16x4_t*)xb, (u16x4_t*)wisb, (u16x4_t*)wigb, (u16x4_t*)woutb,
      (u16x4_t*)wcf, (u16x4_t*)wcb, (u16x4_t*)dtwf, (u16x4_t*)dtwb);

  // 2. in-proj: [xs | silu(z)] = x @ [Wis; Wig]^T
  gemm_bt<<<dim3(3072 / 128, ML / 128, 1), 256, 0, stream>>>(
      xb, wisb, wigb, DI, xsg, ML, 3072, DM, 3072, 0,
      nullptr, nullptr, nullptr, nullptr, nullptr, nullptr, nullptr);

  // 3. causal conv + silu (fwd + reversed)
  conv_kernel<<<(ML * DI) / 256, 256, 0, stream>>>(
      xsg, conv_w, conv_b, conv_wb, conv_bb, xc, xcb);

  // 4. proj GEMMs: [B|C fp32 -> pf] + [dt_low bf16 -> dtl] = xc @ wcat^T
  gemm_bt<<<dim3(1, ML / 128, 2), 256, 0, stream>>>(
      xc, wcf, nullptr, 1 << 30, pf, ML, 128, DI, 32, 5,
      xcb, wcb, pb, dtlf, dtlb, nullptr, nullptr);

  // 5. delta GEMM: delta = softplus(dt_low @ dtW^T + dtb), K=64, fp32 out
  gemm_bt<<<dim3(DI / 128, ML / 128, 2), 256, 0, stream>>>(
      dtlf, dtwf, nullptr, 1 << 30, df, ML, DI, 64, DI, 6,
      dtlb, dtwb, db, nullptr, nullptr, dtb, dtb_b);

  // 6. segmented scan: summaries -> carries -> apply
  scan_sum<<<dim3(DI / 256, BB, 2 * NSEG), 256, 0, stream>>>(
      df, db, xc, xcb, pf, pb, A_log, A_log_b, sdl, bs);
  scan_carry<<<(2 * BB * DI * 16) / 256, 256, 0, stream>>>(
      A_log, A_log_b, sdl, bs);
  scan_apply<<<dim3(DI / 256, BB, 2 * NSEG), 256, 0, stream>>>(
      df, db, xc, xcb, pf, pb, A_log, A_log_b, Dp, Dp_b, bs, yf, ybr);

  // 7. gated combine + un-reverse (in place over yf)
  combine_kernel<<<(ML * DI) / 256, 256, 0, stream>>>(ybr, xsg, yf);

  // 8. out-proj: out = yc @ W_out^T, 64x64 tiles (384 blocks), fp32 to d_out
  gemm_out64<<<dim3(DM / 64, ML / 64, 1), 256, 0, stream>>>(
      yf, woutb, (float*)d_out);
}

// Round 16
// 283.868 us; speedup vs baseline: 1.4984x; 1.0046x over previous
//
#include <hip/hip_runtime.h>
#include <hip/hip_bf16.h>
#include <stdint.h>

// Problem dims (fixed by the reference)
#define DM 768
#define DI 1536
#define DSTATE 16
#define RNK 48
#define BB 2
#define LL 1024
#define ML (BB * LL)  // 2048 rows (b*l flattened)

// segmented scan config
#define NSEG 32
#define SEGL (LL / NSEG)   // 32

typedef unsigned short u16;
typedef __bf16 bf16x8 __attribute__((ext_vector_type(8)));
typedef float f32x4 __attribute__((ext_vector_type(4)));

struct __align__(8) u16x4_t { u16 x, y, z, w; };

__device__ __forceinline__ float b2f(u16 u) {
  union { uint32_t i; float f; } v; v.i = ((uint32_t)u) << 16; return v.f;
}
__device__ __forceinline__ u16 f2b(float f) {
  union { float f; uint32_t i; } v; v.f = f;
  uint32_t r = v.i + 0x7FFFu + ((v.i >> 16) & 1u);  // RNE
  return (u16)(r >> 16);
}
__device__ __forceinline__ float silu_f(float x) { return x / (1.f + __expf(-x)); }
__device__ __forceinline__ float softplus_f(float s) {
  return fmaxf(s, 0.f) + __logf(1.f + __expf(-fabsf(s)));
}
__device__ __forceinline__ u16x4_t cvt4(float4 v) {
  u16x4_t o; o.x = f2b(v.x); o.y = f2b(v.y); o.z = f2b(v.z); o.w = f2b(v.w); return o;
}

// ---------------------------------------------------------------------------
// Fused fp32->bf16 conversion of GEMM operands + small-weight packing.
// wcat (128x1536): rows 0..15=W_B, 16..31=W_C, 32..79=W_dt, 80..127=0
// dtWb (1536x64):  cols 0..47=dtW row, 48..63=0
// ---------------------------------------------------------------------------
#define SEG_X    (ML * DM / 4)
#define SEG_W    (DI * DM / 4)
#define SEG_CAT  (128 * DI / 4)
#define SEG_DTW  (DI * 64 / 4)
__global__ __launch_bounds__(256) void convert_kernel(
    const float4* __restrict__ x, const float4* __restrict__ wis,
    const float4* __restrict__ wig, const float4* __restrict__ wout,
    const float* __restrict__ W_B, const float* __restrict__ W_C,
    const float* __restrict__ W_dt,
    const float* __restrict__ W_B_b, const float* __restrict__ W_C_b,
    const float* __restrict__ W_dt_b,
    const float* __restrict__ dtW, const float* __restrict__ dtW_b,
    u16x4_t* __restrict__ xb, u16x4_t* __restrict__ wisb,
    u16x4_t* __restrict__ wigb, u16x4_t* __restrict__ woutb,
    u16x4_t* __restrict__ wcf, u16x4_t* __restrict__ wcb,
    u16x4_t* __restrict__ dtwf, u16x4_t* __restrict__ dtwb)
{
  int idx = blockIdx.x * 256 + threadIdx.x;
  if (idx < SEG_X) { xb[idx] = cvt4(x[idx]); return; }
  idx -= SEG_X;
  if (idx < SEG_W) { wisb[idx] = cvt4(wis[idx]); return; }
  idx -= SEG_W;
  if (idx < SEG_W) { wigb[idx] = cvt4(wig[idx]); return; }
  idx -= SEG_W;
  if (idx < SEG_W) { woutb[idx] = cvt4(wout[idx]); return; }
  idx -= SEG_W;
  if (idx < 2 * SEG_CAT) {
    int dir = idx / SEG_CAT;
    int rem = idx % SEG_CAT;
    int row = rem / (DI / 4), k4 = rem % (DI / 4);
    const float* src = nullptr;
    if (row < 16)      src = (dir ? W_B_b  : W_B)  + (size_t)row * DI + k4 * 4;
    else if (row < 32) src = (dir ? W_C_b  : W_C)  + (size_t)(row - 16) * DI + k4 * 4;
    else if (row < 80) src = (dir ? W_dt_b : W_dt) + (size_t)(row - 32) * DI + k4 * 4;
    u16x4_t o;
    if (src) o = cvt4(*(const float4*)src);
    else { o.x = 0; o.y = 0; o.z = 0; o.w = 0; }
    (dir ? wcb : wcf)[rem] = o;
    return;
  }
  idx -= 2 * SEG_CAT;
  int dir = idx / SEG_DTW;
  int rem = idx % SEG_DTW;
  int d = rem / 16, r4 = rem % 16;
  const float* Dw = dir ? dtW_b : dtW;
  u16x4_t o;
  if (r4 < 12) o = cvt4(*(const float4*)(Dw + (size_t)d * RNK + r4 * 4));
  else { o.x = 0; o.y = 0; o.z = 0; o.w = 0; }
  (dir ? dtwb : dtwf)[rem] = o;
}

// ---------------------------------------------------------------------------
// Generic bf16 GEMM: C = A (MxK) @ B^T (NxK). 128x128 tile, 4 waves,
// 16x16x32 MFMA, reg double-buffer pipeline (round 9).
// epi: 0 bf16 (dual-B silu via B1/Nsplit) | 2 fp32 |
//      5 proj: col<32 fp32->Cout(ld 32), 32<=col<96 bf16->Caux(ld 64), else skip
//      6 delta: BF16 softplus(acc + ebias[col]) -> Cout (ld ldc)  [r16: was fp32]
// blockIdx.z==1 switches to (A2,B2,C2,Caux2,ebias2).
// r13/r14 lesson: never fuse elementwise stages into grid-starved GEMMs.
// ---------------------------------------------------------------------------
__global__ __launch_bounds__(256) void gemm_bt(
    const u16* __restrict__ A, const u16* __restrict__ B0,
    const u16* __restrict__ B1, int Nsplit,
    void* __restrict__ Cout, int M, int N, int K, int ldc, int epi,
    const u16* __restrict__ A2, const u16* __restrict__ B2,
    void* __restrict__ C2,
    u16* __restrict__ Caux, u16* __restrict__ Caux2,
    const float* __restrict__ ebias, const float* __restrict__ ebias2)
{
  if (blockIdx.z) { A = A2; B0 = B2; Cout = C2; Caux = Caux2; ebias = ebias2; }
  __shared__ alignas(16) u16 As[128 * 32];
  __shared__ alignas(16) u16 Bs[128 * 32];
  const int tid = threadIdx.x;
  const int wave = tid >> 6, lane = tid & 63;
  const int bm = blockIdx.y * 128;
  const int bn = blockIdx.x * 128;

  const u16* Bmat = B0;
  int ncol0 = bn;
  int epi_l = epi;
  if (B1 != nullptr && bn >= Nsplit) { Bmat = B1; ncol0 = bn - Nsplit; epi_l = 1; }

  const int c0 = tid, c1 = tid + 256;
  const u16* gA0 = A + (size_t)(bm + (c0 >> 2)) * K + (c0 & 3) * 8;
  const u16* gA1 = A + (size_t)(bm + (c1 >> 2)) * K + (c1 & 3) * 8;
  const u16* gB0 = Bmat + (size_t)(ncol0 + (c0 >> 2)) * K + (c0 & 3) * 8;
  const u16* gB1 = Bmat + (size_t)(ncol0 + (c1 >> 2)) * K + (c1 & 3) * 8;
  uint4* lA0 = (uint4*)&As[c0 * 8]; uint4* lA1 = (uint4*)&As[c1 * 8];
  uint4* lB0 = (uint4*)&Bs[c0 * 8]; uint4* lB1 = (uint4*)&Bs[c1 * 8];

  const int wm = (wave & 1) * 64, wn = (wave >> 1) * 64;
  const int rl = lane & 15, q = lane >> 4;

  f32x4 acc[4][4];
#pragma unroll
  for (int i = 0; i < 4; ++i)
#pragma unroll
    for (int j = 0; j < 4; ++j) acc[i][j] = (f32x4){0.f, 0.f, 0.f, 0.f};

  const bf16x8* AsV = (const bf16x8*)As;
  const bf16x8* BsV = (const bf16x8*)Bs;

  uint4 ra0 = *(const uint4*)(gA0);
  uint4 ra1 = *(const uint4*)(gA1);
  uint4 rb0 = *(const uint4*)(gB0);
  uint4 rb1 = *(const uint4*)(gB1);

  for (int k0 = 0; k0 < K; k0 += 32) {
    *lA0 = ra0; *lA1 = ra1; *lB0 = rb0; *lB1 = rb1;
    __syncthreads();
    if (k0 + 32 < K) {
      ra0 = *(const uint4*)(gA0 + k0 + 32);
      ra1 = *(const uint4*)(gA1 + k0 + 32);
      rb0 = *(const uint4*)(gB0 + k0 + 32);
      rb1 = *(const uint4*)(gB1 + k0 + 32);
    }
    bf16x8 af[4], bfv[4];
#pragma unroll
    for (int s = 0; s < 4; ++s) {
      af[s]  = AsV[(wm + s * 16 + rl) * 4 + q];
      bfv[s] = BsV[(wn + s * 16 + rl) * 4 + q];
    }
#pragma unroll
    for (int i = 0; i < 4; ++i)
#pragma unroll
      for (int j = 0; j < 4; ++j)
        acc[i][j] = __builtin_amdgcn_mfma_f32_16x16x32_bf16(af[i], bfv[j], acc[i][j], 0, 0, 0);
    __syncthreads();
  }

  // epilogue: C/D layout col=lane&15, row=(lane>>4)*4+reg
#pragma unroll
  for (int i = 0; i < 4; ++i) {
#pragma unroll
    for (int j = 0; j < 4; ++j) {
#pragma unroll
      for (int r = 0; r < 4; ++r) {
        int row = bm + wm + i * 16 + q * 4 + r;
        int col = bn + wn + j * 16 + rl;
        float v = acc[i][j][r];
        if (epi_l == 1) v = silu_f(v);
        if (epi == 5) {
          if (col < 32)      ((float*)Cout)[(size_t)row * 32 + col] = v;
          else if (col < 96) Caux[(size_t)row * 64 + (col - 32)] = f2b(v);
        } else if (epi == 6) {
          ((u16*)Cout)[(size_t)row * ldc + col] = f2b(softplus_f(v + ebias[col]));
        } else if (epi == 2) {
          ((float*)Cout)[(size_t)row * ldc + col] = v;
        } else {
          ((u16*)Cout)[(size_t)row * ldc + col] = f2b(v);
        }
      }
    }
  }
}

// ---------------------------------------------------------------------------
// Out-proj GEMM, 64x64 tile / K-tile 64 (validated r15): grid (12,32)=384
// blocks. Wave w owns N-strip [16w,16w+16); LDS rows padded to 72 (144B
// stride -> 2-way bank aliasing, free per m136). fp32 out.
// ---------------------------------------------------------------------------
__global__ __launch_bounds__(256) void gemm_out64(
    const u16* __restrict__ A, const u16* __restrict__ Bw,
    float* __restrict__ out)
{
  __shared__ alignas(16) u16 As[64 * 72];
  __shared__ alignas(16) u16 Bs[64 * 72];
  const int tid = threadIdx.x;
  const int wave = tid >> 6, lane = tid & 63;
  const int bm = blockIdx.y * 64;
  const int bn = blockIdx.x * 64;

  const int c0 = tid, c1 = tid + 256;
  const u16* gA0 = A + (size_t)(bm + (c0 >> 3)) * DI + (c0 & 7) * 8;
  const u16* gA1 = A + (size_t)(bm + (c1 >> 3)) * DI + (c1 & 7) * 8;
  const u16* gB0 = Bw + (size_t)(bn + (c0 >> 3)) * DI + (c0 & 7) * 8;
  const u16* gB1 = Bw + (size_t)(bn + (c1 >> 3)) * DI + (c1 & 7) * 8;
  uint4* lA0 = (uint4*)&As[(c0 >> 3) * 72 + (c0 & 7) * 8];
  uint4* lA1 = (uint4*)&As[(c1 >> 3) * 72 + (c1 & 7) * 8];
  uint4* lB0 = (uint4*)&Bs[(c0 >> 3) * 72 + (c0 & 7) * 8];
  uint4* lB1 = (uint4*)&Bs[(c1 >> 3) * 72 + (c1 & 7) * 8];

  const int rl = lane & 15, q = lane >> 4;

  f32x4 acc[4];
#pragma unroll
  for (int s = 0; s < 4; ++s) acc[s] = (f32x4){0.f, 0.f, 0.f, 0.f};

  uint4 ra0 = *(const uint4*)gA0, ra1 = *(const uint4*)gA1;
  uint4 rb0 = *(const uint4*)gB0, rb1 = *(const uint4*)gB1;

  for (int k0 = 0; k0 < DI; k0 += 64) {
    *lA0 = ra0; *lA1 = ra1; *lB0 = rb0; *lB1 = rb1;
    __syncthreads();
    if (k0 + 64 < DI) {
      ra0 = *(const uint4*)(gA0 + k0 + 64);
      ra1 = *(const uint4*)(gA1 + k0 + 64);
      rb0 = *(const uint4*)(gB0 + k0 + 64);
      rb1 = *(const uint4*)(gB1 + k0 + 64);
    }
    bf16x8 bf[2], af;
#pragma unroll
    for (int c = 0; c < 2; ++c)
      bf[c] = *(const bf16x8*)&Bs[(wave * 16 + rl) * 72 + c * 32 + q * 8];
#pragma unroll
    for (int s = 0; s < 4; ++s) {
#pragma unroll
      for (int c = 0; c < 2; ++c) {
        af = *(const bf16x8*)&As[(s * 16 + rl) * 72 + c * 32 + q * 8];
        acc[s] = __builtin_amdgcn_mfma_f32_16x16x32_bf16(af, bf[c], acc[s], 0, 0, 0);
      }
    }
    __syncthreads();
  }

#pragma unroll
  for (int s = 0; s < 4; ++s) {
#pragma unroll
    for (int r = 0; r < 4; ++r) {
      int row = bm + s * 16 + q * 4 + r;
      int col = bn + wave * 16 + rl;
      out[(size_t)row * DM + col] = acc[s][r];
    }
  }
}

// ---------------------------------------------------------------------------
// Causal depthwise conv (K=4, fp32 weights) + SiLU, fwd + reversed.
// 12288 blocks — keep standalone (r13).
// ---------------------------------------------------------------------------
__global__ void conv_kernel(
    const u16* __restrict__ xsg,
    const float* __restrict__ cw, const float* __restrict__ cb,
    const float* __restrict__ cwb, const float* __restrict__ cbb,
    u16* __restrict__ xc, u16* __restrict__ xcb)
{
  int idx = blockIdx.x * 256 + threadIdx.x;      // over ML*DI
  int d = idx % DI;
  int row = idx / DI;
  int l = row % LL, b = row / LL;
  const u16* base = xsg + (size_t)b * LL * 3072 + d;

  float4 wf = *(const float4*)(cw + d * 4);
  float4 wb = *(const float4*)(cwb + d * 4);
  float wfk[4] = {wf.x, wf.y, wf.z, wf.w};
  float wbk[4] = {wb.x, wb.y, wb.z, wb.w};

  float accf = cb[d];
  float accb = cbb[d];
#pragma unroll
  for (int k = 0; k < 4; ++k) {
    int ls = l - 3 + k;
    if (ls >= 0) {
      accf += wfk[k] * b2f(base[(size_t)ls * 3072]);
      accb += wbk[k] * b2f(base[(size_t)(LL - 1 - ls) * 3072]);
    }
  }
  xc[idx]  = f2b(silu_f(accf));
  xcb[idx] = f2b(silu_f(accb));
}

// ---------------------------------------------------------------------------
// y_comb[l] = 0.5 * silu(z[l]) * (y_f[l] + y_b_rev[L-1-l]); in-place over yf.
// ---------------------------------------------------------------------------
__global__ void combine_kernel(
    const u16* __restrict__ ybr, const u16* __restrict__ xsg, u16* yf)
{
  int idx = blockIdx.x * 256 + threadIdx.x;      // over ML*DI
  int d = idx % DI;
  int row = idx / DI;
  int l = row % LL, b = row / LL;
  float g = b2f(xsg[(size_t)row * 3072 + DI + d]);
  float vb = b2f(ybr[((size_t)b * LL + (LL - 1 - l)) * DI + d]);
  float v = 0.5f * (b2f(yf[idx]) + vb) * g;
  yf[idx] = f2b(v);
}

// ---------------------------------------------------------------------------
// Segmented scan, phase A: per (dir,b,seg,d) compute Sdelta and local
// end-state h_local[16] (h_in=0). delta precomputed BF16 (softplus in
// delta-GEMM epilogue). B from proj (ld 32, cols 0..15).
// ---------------------------------------------------------------------------
__global__ __launch_bounds__(256) void scan_sum(
    const u16* __restrict__ df, const u16* __restrict__ db,
    const u16* __restrict__ xcf, const u16* __restrict__ xcb,
    const float* __restrict__ pf, const float* __restrict__ pb,
    const float* __restrict__ A_log, const float* __restrict__ A_log_b,
    float* __restrict__ sdl, float* __restrict__ bs)
{
  const int dir = blockIdx.z / NSEG, seg = blockIdx.z % NSEG;
  const u16* delta = dir ? db : df;
  const u16* xc = dir ? xcb : xcf;
  const float* proj = dir ? pb : pf;
  const float* Al = dir ? A_log_b : A_log;
  const int b = blockIdx.y;
  const int d = blockIdx.x * 256 + threadIdx.x;
  const int l0 = seg * SEGL;

  __shared__ float Bsh[SEGL][16];
  for (int i = threadIdx.x; i < SEGL * 16; i += 256) {
    int l = i >> 4, n = i & 15;
    Bsh[l][n] = proj[((size_t)b * LL + l0 + l) * 32 + n];
  }
  __syncthreads();

  float An[16];
#pragma unroll
  for (int n = 0; n < 16; ++n) An[n] = -__expf(Al[d * 16 + n]);

  float h[16];
#pragma unroll
  for (int n = 0; n < 16; ++n) h[n] = 0.f;
  float S = 0.f;

  const u16* dbase = delta + ((size_t)b * LL + l0) * DI + d;
  const u16* xbase = xc + ((size_t)b * LL + l0) * DI + d;

  for (int g = 0; g < SEGL; g += 4) {
    float dl4[4], dx4[4];
#pragma unroll
    for (int j = 0; j < 4; ++j) {
      float dv = b2f(dbase[(size_t)(g + j) * DI]);
      float xv = b2f(xbase[(size_t)(g + j) * DI]);
      dl4[j] = dv; dx4[j] = dv * xv;
    }
#pragma unroll
    for (int j = 0; j < 4; ++j) {
      S += dl4[j];
#pragma unroll
      for (int n = 0; n < 16; ++n)
        h[n] = __expf(dl4[j] * An[n]) * h[n] + dx4[j] * Bsh[g + j][n];
    }
  }

  size_t base = (((size_t)dir * BB + b) * NSEG + seg) * DI + d;
  sdl[base] = S;
#pragma unroll
  for (int n = 0; n < 16; ++n) bs[base * 16 + n] = h[n];
}

// ---------------------------------------------------------------------------
// Phase B: compose segment summaries into carry-ins (bs overwritten in place).
// ---------------------------------------------------------------------------
__global__ __launch_bounds__(256) void scan_carry(
    const float* __restrict__ A_log, const float* __restrict__ A_log_b,
    const float* __restrict__ sdl, float* __restrict__ bs)
{
  int idx = blockIdx.x * 256 + threadIdx.x;   // over 2*BB*DI*16
  int n = idx & 15;
  int t = idx >> 4;
  int d = t % DI;
  int b = (t / DI) % BB;
  int dir = t / (DI * BB);
  const float* Al = dir ? A_log_b : A_log;
  float An = -__expf(Al[d * 16 + n]);
  float h = 0.f;
  for (int s = 0; s < NSEG; ++s) {
    size_t base = (((size_t)dir * BB + b) * NSEG + s) * DI + d;
    float S = sdl[base];
    float bv = bs[base * 16 + n];
    bs[base * 16 + n] = h;
    h = __expf(S * An) * h + bv;
  }
}

// ---------------------------------------------------------------------------
// Phase C: redo recurrence from carry-in, compute y. B/C from proj ld 32.
// delta BF16.
// ---------------------------------------------------------------------------
__global__ __launch_bounds__(256) void scan_apply(
    const u16* __restrict__ df, const u16* __restrict__ db,
    const u16* __restrict__ xcf, const u16* __restrict__ xcb,
    const float* __restrict__ pf, const float* __restrict__ pb,
    const float* __restrict__ A_log, const float* __restrict__ A_log_b,
    const float* __restrict__ Dp, const float* __restrict__ Dp_b,
    const float* __restrict__ bs,
    u16* __restrict__ y_f, u16* __restrict__ y_b)
{
  const int dir = blockIdx.z / NSEG, seg = blockIdx.z % NSEG;
  const u16* delta = dir ? db : df;
  const u16* xc = dir ? xcb : xcf;
  const float* proj = dir ? pb : pf;
  const float* Al = dir ? A_log_b : A_log;
  const float* Dpp = dir ? Dp_b : Dp;
  u16* y = dir ? y_b : y_f;
  const int b = blockIdx.y;
  const int d = blockIdx.x * 256 + threadIdx.x;
  const int l0 = seg * SEGL;

  __shared__ float BCsh[SEGL][32];            // [l][0:16)=B, [16:32)=C
  for (int i = threadIdx.x; i < SEGL * 32; i += 256) {
    int l = i >> 5, j = i & 31;
    BCsh[l][j] = proj[((size_t)b * LL + l0 + l) * 32 + j];
  }
  __syncthreads();

  float An[16];
#pragma unroll
  for (int n = 0; n < 16; ++n) An[n] = -__expf(Al[d * 16 + n]);
  const float Dv = Dpp[d];

  float h[16];
  size_t cbase = (((size_t)dir * BB + b) * NSEG + seg) * DI + d;
#pragma unroll
  for (int n = 0; n < 16; ++n) h[n] = bs[cbase * 16 + n];

  const u16* dbase = delta + ((size_t)b * LL + l0) * DI + d;
  const u16* xbase = xc + ((size_t)b * LL + l0) * DI + d;
  u16* ybase = y + ((size_t)b * LL + l0) * DI + d;

  for (int g = 0; g < SEGL; g += 4) {
    float dl4[4], xv4[4];
#pragma unroll
    for (int j = 0; j < 4; ++j) {
      dl4[j] = b2f(dbase[(size_t)(g + j) * DI]);
      xv4[j] = b2f(xbase[(size_t)(g + j) * DI]);
    }
#pragma unroll
    for (int j = 0; j < 4; ++j) {
      float dx = dl4[j] * xv4[j];
      float yv = 0.f;
#pragma unroll
      for (int n = 0; n < 16; ++n) {
        h[n] = __expf(dl4[j] * An[n]) * h[n] + dx * BCsh[g + j][n];
        yv += h[n] * BCsh[g + j][16 + n];
      }
      ybase[(size_t)(g + j) * DI] = f2b(yv + Dv * xv4[j]);
    }
  }
}

// ---------------------------------------------------------------------------
extern "C" void kernel_launch(void* const* d_in, const int* in_sizes, int n_in,
                              void* d_out, int out_size, void* d_ws, size_t ws_size,
                              hipStream_t stream)
{
  const float* x       = (const float*)d_in[0];
  const float* Wis     = (const float*)d_in[1];
  const float* Wig     = (const float*)d_in[2];
  const float* conv_w  = (const float*)d_in[3];
  const float* conv_b  = (const float*)d_in[4];
  const float* conv_wb = (const float*)d_in[5];
  const float* conv_bb = (const float*)d_in[6];
  const float* W_dt    = (const float*)d_in[7];
  const float* W_B     = (const float*)d_in[8];
  const float* W_C     = (const float*)d_in[9];
  const float* dtW     = (const float*)d_in[10];
  const float* dtb     = (const float*)d_in[11];
  const float* A_log   = (const float*)d_in[12];
  const float* Dp      = (const float*)d_in[13];
  const float* W_dt_b  = (const float*)d_in[14];
  const float* W_B_b   = (const float*)d_in[15];
  const float* W_C_b   = (const float*)d_in[16];
  const float* dtW_b   = (const float*)d_in[17];
  const float* dtb_b   = (const float*)d_in[18];
  const float* A_log_b = (const float*)d_in[19];
  const float* Dp_b    = (const float*)d_in[20];
  const float* W_out   = (const float*)d_in[21];

  char* ws = (char*)d_ws;
  size_t off = 0;
  auto alloc = [&](size_t bytes) -> char* {
    char* p = ws + off; off += (bytes + 255) & ~(size_t)255; return p;
  };
  u16*   xb    = (u16*)alloc((size_t)ML * DM * 2);
  u16*   wisb  = (u16*)alloc((size_t)DI * DM * 2);
  u16*   wigb  = (u16*)alloc((size_t)DI * DM * 2);
  u16*   woutb = (u16*)alloc((size_t)DM * DI * 2);
  u16*   xsg = (u16*)alloc((size_t)ML * 3072 * 2);     // [xs | silu(z)]
  u16*   xc  = (u16*)alloc((size_t)ML * DI * 2);
  u16*   xcb = (u16*)alloc((size_t)ML * DI * 2);       // reversed space
  u16*   wcf = (u16*)alloc((size_t)128 * DI * 2);      // [B|C|W_dt|0]
  u16*   wcb = (u16*)alloc((size_t)128 * DI * 2);
  u16*   dtwf = (u16*)alloc((size_t)DI * 64 * 2);      // dtW bf16 K-padded
  u16*   dtwb = (u16*)alloc((size_t)DI * 64 * 2);
  float* pf  = (float*)alloc((size_t)ML * 32 * 4);     // [B|C] fp32, ld 32
  float* pb  = (float*)alloc((size_t)ML * 32 * 4);
  u16*   dtlf = (u16*)alloc((size_t)ML * 64 * 2);      // dt_low bf16, ld 64
  u16*   dtlb = (u16*)alloc((size_t)ML * 64 * 2);
  u16*   df  = (u16*)alloc((size_t)ML * DI * 2);       // delta bf16 (r16)
  u16*   db  = (u16*)alloc((size_t)ML * DI * 2);
  u16*   yf  = (u16*)alloc((size_t)ML * DI * 2);       // holds combined y after step 7
  u16*   ybr = (u16*)alloc((size_t)ML * DI * 2);       // reversed space
  float* sdl = (float*)alloc((size_t)2 * BB * NSEG * DI * 4);
  float* bs  = (float*)alloc((size_t)2 * BB * NSEG * DI * 16 * 4);

  // 1. fp32->bf16 conversion + weight packing (wcat, dtWb)
  const int conv_total = SEG_X + 3 * SEG_W + 2 * SEG_CAT + 2 * SEG_DTW;
  convert_kernel<<<(conv_total + 255) / 256, 256, 0, stream>>>(
      (const float4*)x, (const float4*)Wis, (const float4*)Wig, (const float4*)W_out,
      W_B, W_C, W_dt, W_B_b, W_C_b, W_dt_b, dtW, dtW_b,
      (u16x4_t*)xb, (u16x4_t*)wisb, (u16x4_t*)wigb, (u16x4_t*)woutb,
      (u16x4_t*)wcf, (u16x4_t*)wcb, (u16x4_t*)dtwf, (u16x4_t*)dtwb);

  // 2. in-proj: [xs | silu(z)] = x @ [Wis; Wig]^T
  gemm_bt<<<dim3(3072 / 128, ML / 128, 1), 256, 0, stream>>>(
      xb, wisb, wigb, DI, xsg, ML, 3072, DM, 3072, 0,
      nullptr, nullptr, nullptr, nullptr, nullptr, nullptr, nullptr);

  // 3. causal conv + silu (fwd + reversed)
  conv_kernel<<<(ML * DI) / 256, 256, 0, stream>>>(
      xsg, conv_w, conv_b, conv_wb, conv_bb, xc, xcb);

  // 4. proj GEMMs: [B|C fp32 -> pf] + [dt_low bf16 -> dtl] = xc @ wcat^T
  gemm_bt<<<dim3(1, ML / 128, 2), 256, 0, stream>>>(
      xc, wcf, nullptr, 1 << 30, pf, ML, 128, DI, 32, 5,
      xcb, wcb, pb, dtlf, dtlb, nullptr, nullptr);

  // 5. delta GEMM: delta = softplus(dt_low @ dtW^T + dtb), K=64, bf16 out
  gemm_bt<<<dim3(DI / 128, ML / 128, 2), 256, 0, stream>>>(
      dtlf, dtwf, nullptr, 1 << 30, df, ML, DI, 64, DI, 6,
      dtlb, dtwb, db, nullptr, nullptr, dtb, dtb_b);

  // 6. segmented scan: summaries -> carries -> apply
  scan_sum<<<dim3(DI / 256, BB, 2 * NSEG), 256, 0, stream>>>(
      df, db, xc, xcb, pf, pb, A_log, A_log_b, sdl, bs);
  scan_carry<<<(2 * BB * DI * 16) / 256, 256, 0, stream>>>(
      A_log, A_log_b, sdl, bs);
  scan_apply<<<dim3(DI / 256, BB, 2 * NSEG), 256, 0, stream>>>(
      df, db, xc, xcb, pf, pb, A_log, A_log_b, Dp, Dp_b, bs, yf, ybr);

  // 7. gated combine + un-reverse (in place over yf)
  combine_kernel<<<(ML * DI) / 256, 256, 0, stream>>>(ybr, xsg, yf);

  // 8. out-proj: out = yc @ W_out^T, 64x64 tiles (384 blocks), fp32 to d_out
  gemm_out64<<<dim3(DM / 64, ML / 64, 1), 256, 0, stream>>>(
      yf, woutb, (float*)d_out);
}